// Round 1
// baseline (1576.729 us; speedup 1.0000x reference)
//
#include <hip/hip_runtime.h>
#include <math.h>

// Topoformer-Mamba block, fp32 correctness-first baseline.
// B=2, L=2048, D_MODEL=1024, D_INNER=2048, N(state)=16, DT_RANK=64, d_conv=4.

#define DMODEL 1024
#define DINNER 2048
#define NSTATE 16
#define DTRANK 64
#define BATCH  2
#define SEQ    2048
#define ROWS   (BATCH*SEQ)     // 4096
#define NC     64              // scan chunks
#define TS     (SEQ/NC)        // 32 steps per chunk
#define LN_EPS 1e-5f

__device__ __forceinline__ float silu_f(float x) { return x / (1.f + __expf(-x)); }

// ---------------- LayerNorm (one block per row) ----------------
__global__ __launch_bounds__(256) void ln_kernel(const float* __restrict__ x,
                                                 const float* __restrict__ g,
                                                 const float* __restrict__ bta,
                                                 float* __restrict__ out)
{
    int row = blockIdx.x;
    const float* xr = x + (size_t)row * DMODEL;
    float4 v = ((const float4*)xr)[threadIdx.x];
    float s  = v.x + v.y + v.z + v.w;
    float ss = v.x*v.x + v.y*v.y + v.z*v.z + v.w*v.w;
    #pragma unroll
    for (int off = 32; off; off >>= 1) { s += __shfl_down(s, off); ss += __shfl_down(ss, off); }
    __shared__ float s_s[4], s_ss[4];
    int lane = threadIdx.x & 63, w = threadIdx.x >> 6;
    if (lane == 0) { s_s[w] = s; s_ss[w] = ss; }
    __syncthreads();
    float ts = 0.f, tss = 0.f;
    #pragma unroll
    for (int i = 0; i < 4; i++) { ts += s_s[i]; tss += s_ss[i]; }
    float mu  = ts / (float)DMODEL;
    float var = tss / (float)DMODEL - mu * mu;
    float rstd = rsqrtf(var + LN_EPS);
    float4 gv = ((const float4*)g)[threadIdx.x];
    float4 bv = ((const float4*)bta)[threadIdx.x];
    float4 o;
    o.x = (v.x - mu) * rstd * gv.x + bv.x;
    o.y = (v.y - mu) * rstd * gv.y + bv.y;
    o.z = (v.z - mu) * rstd * gv.z + bv.z;
    o.w = (v.w - mu) * rstd * gv.w + bv.w;
    ((float4*)(out + (size_t)row * DMODEL))[threadIdx.x] = o;
}

// ---------------- Generic fp32 GEMM: C = act(A@B [+bias] [+res]) ----------------
// 128x128 tile, BK=8, 256 threads, 8x8 micro-tile per thread (split 2x2 of 4x4).
// ACT: 0=none, 1=softplus. res assumed same leading dim as C (ldc).
template<int ACT, bool HAS_BIAS, bool HAS_RES>
__global__ __launch_bounds__(256) void gemm_f32(
    const float* __restrict__ A, const float* __restrict__ B, float* __restrict__ C,
    const float* __restrict__ bias, const float* __restrict__ res,
    int M, int N, int K, int lda, int ldb, int ldc)
{
    __shared__ float As[8][128];
    __shared__ float Bs[8][128];
    const int tid = threadIdx.x;
    const int m0 = blockIdx.y * 128, n0 = blockIdx.x * 128;
    const int tx = tid & 15, ty = tid >> 4;
    const int arow = tid >> 1, akq = (tid & 1) << 2;   // A tile: 128 rows x 8k, float4 along K
    const int bk = tid >> 5, bn4 = (tid & 31) << 2;    // B tile: 8k x 128 cols, float4 along N
    float acc[8][8];
    #pragma unroll
    for (int i = 0; i < 8; i++)
        #pragma unroll
        for (int j = 0; j < 8; j++) acc[i][j] = 0.f;

    const float* Aptr = A + (size_t)(m0 + arow) * lda + akq;
    const float* Bptr = B + (size_t)bk * ldb + n0 + bn4;
    const bool bfull = (n0 + bn4 + 3) < N;

    for (int k0 = 0; k0 < K; k0 += 8) {
        float4 av = *(const float4*)(Aptr + k0);
        float4 bv;
        if (bfull) {
            bv = *(const float4*)(Bptr + (size_t)k0 * ldb);
        } else {
            const float* bp = Bptr + (size_t)k0 * ldb;
            bv.x = (n0 + bn4 + 0 < N) ? bp[0] : 0.f;
            bv.y = (n0 + bn4 + 1 < N) ? bp[1] : 0.f;
            bv.z = (n0 + bn4 + 2 < N) ? bp[2] : 0.f;
            bv.w = (n0 + bn4 + 3 < N) ? bp[3] : 0.f;
        }
        __syncthreads();
        As[akq + 0][arow] = av.x; As[akq + 1][arow] = av.y;
        As[akq + 2][arow] = av.z; As[akq + 3][arow] = av.w;
        *(float4*)&Bs[bk][bn4] = bv;
        __syncthreads();
        #pragma unroll
        for (int kk = 0; kk < 8; kk++) {
            float a[8], b[8];
            *(float4*)&a[0] = *(const float4*)&As[kk][ty * 4];
            *(float4*)&a[4] = *(const float4*)&As[kk][64 + ty * 4];
            *(float4*)&b[0] = *(const float4*)&Bs[kk][tx * 4];
            *(float4*)&b[4] = *(const float4*)&Bs[kk][64 + tx * 4];
            #pragma unroll
            for (int i = 0; i < 8; i++)
                #pragma unroll
                for (int j = 0; j < 8; j++)
                    acc[i][j] = fmaf(a[i], b[j], acc[i][j]);
        }
    }
    #pragma unroll
    for (int ih = 0; ih < 2; ih++)
        #pragma unroll
        for (int i = 0; i < 4; i++) {
            int row = m0 + ih * 64 + ty * 4 + i;
            #pragma unroll
            for (int jh = 0; jh < 2; jh++)
                #pragma unroll
                for (int j = 0; j < 4; j++) {
                    int col = n0 + jh * 64 + tx * 4 + j;
                    if (col < N) {
                        float c = acc[ih * 4 + i][jh * 4 + j];
                        if (HAS_BIAS) c += bias[col];
                        if (HAS_RES)  c += res[(size_t)row * ldc + col];
                        if (ACT == 1) c = logf(1.f + __expf(c));  // softplus
                        C[(size_t)row * ldc + col] = c;
                    }
                }
        }
}

// ---------------- Causal depthwise conv (d_conv=4) + SiLU ----------------
// reads u_raw = xz[:, 0:2048] (ld 4096), writes u [ROWS, 2048]
__global__ __launch_bounds__(256) void conv_silu_kernel(
    const float* __restrict__ xz, const float* __restrict__ w,
    const float* __restrict__ b, float* __restrict__ u)
{
    size_t idx = (size_t)blockIdx.x * 256 + threadIdx.x;  // ROWS*DINNER
    int d = (int)(idx & (DINNER - 1));
    int r = (int)(idx >> 11);
    int t = r & (SEQ - 1);
    float4 wv = *(const float4*)(w + (size_t)d * 4);
    float acc = b[d];
    const float* wf = (const float*)&wv;
    #pragma unroll
    for (int j = 0; j < 4; j++) {
        int tt = t - 3 + j;
        if (tt >= 0)
            acc = fmaf(xz[(size_t)(r - 3 + j) * 4096 + d], wf[j], acc);
    }
    u[idx] = silu_f(acc);
}

// ---------------- Chunked selective scan ----------------
// Phase A: per (b, chunk, d): local scan from 0; store final local state S and decay product P.
__global__ __launch_bounds__(256) void scan_phaseA(
    const float* __restrict__ delta, int ldd,
    const float* __restrict__ u,
    const float* __restrict__ xdbl,   // [ROWS,96]; B at +64
    const float* __restrict__ A_log,
    float* __restrict__ S, float* __restrict__ P)
{
    int d = blockIdx.x * 256 + threadIdx.x;
    int c = blockIdx.y, b = blockIdx.z;
    float Ad[NSTATE];
    #pragma unroll
    for (int n = 0; n < NSTATE; n++) Ad[n] = -__expf(A_log[(size_t)d * NSTATE + n]);
    float hs[NSTATE], pr[NSTATE];
    #pragma unroll
    for (int n = 0; n < NSTATE; n++) { hs[n] = 0.f; pr[n] = 1.f; }
    int r0 = b * SEQ + c * TS;
    for (int t = 0; t < TS; t++) {
        int r = r0 + t;
        float dlt = delta[(size_t)r * ldd + d];
        float uu  = u[(size_t)r * DINNER + d];
        const float* bm = xdbl + (size_t)r * 96 + DTRANK;
        float du = dlt * uu;
        #pragma unroll
        for (int n = 0; n < NSTATE; n++) {
            float dA = __expf(dlt * Ad[n]);
            hs[n] = fmaf(dA, hs[n], du * bm[n]);
            pr[n] *= dA;
        }
    }
    size_t base = ((size_t)(b * NC + c) * DINNER + d) * NSTATE;
    #pragma unroll
    for (int n = 0; n < NSTATE; n += 4) {
        *(float4*)(S + base + n) = make_float4(hs[n], hs[n+1], hs[n+2], hs[n+3]);
        *(float4*)(P + base + n) = make_float4(pr[n], pr[n+1], pr[n+2], pr[n+3]);
    }
}

// Phase B: sequential combine over chunks (per (b,d)); emits carry-in state per chunk.
__global__ __launch_bounds__(256) void scan_phaseB(
    const float* __restrict__ P, const float* __restrict__ S, float* __restrict__ Hin)
{
    int idx = blockIdx.x * 256 + threadIdx.x;  // BATCH*DINNER
    int d = idx & (DINNER - 1);
    int b = idx >> 11;
    float h[NSTATE];
    #pragma unroll
    for (int n = 0; n < NSTATE; n++) h[n] = 0.f;
    for (int c = 0; c < NC; c++) {
        size_t base = ((size_t)(b * NC + c) * DINNER + d) * NSTATE;
        #pragma unroll
        for (int n = 0; n < NSTATE; n += 4)
            *(float4*)(Hin + base + n) = make_float4(h[n], h[n+1], h[n+2], h[n+3]);
        #pragma unroll
        for (int n = 0; n < NSTATE; n++)
            h[n] = fmaf(P[base + n], h[n], S[base + n]);
    }
}

// Phase C: replay scan with carry-in; fuse y = (scan_y + u*D) * silu(z); write in-place over u.
__global__ __launch_bounds__(256) void scan_phaseC(
    const float* __restrict__ delta, int ldd,
    float* __restrict__ u,            // in: u; out: yz (in-place)
    const float* __restrict__ xdbl,   // B at +64, C at +80
    const float* __restrict__ A_log,
    const float* __restrict__ Hin,
    const float* __restrict__ Dp,
    const float* __restrict__ xz)     // z at col 2048+d, ld 4096
{
    int d = blockIdx.x * 256 + threadIdx.x;
    int c = blockIdx.y, b = blockIdx.z;
    float Ad[NSTATE];
    #pragma unroll
    for (int n = 0; n < NSTATE; n++) Ad[n] = -__expf(A_log[(size_t)d * NSTATE + n]);
    float hs[NSTATE];
    size_t hbase = ((size_t)(b * NC + c) * DINNER + d) * NSTATE;
    #pragma unroll
    for (int n = 0; n < NSTATE; n++) hs[n] = Hin[hbase + n];
    float Dd = Dp[d];
    int r0 = b * SEQ + c * TS;
    for (int t = 0; t < TS; t++) {
        int r = r0 + t;
        float dlt = delta[(size_t)r * ldd + d];
        float uu  = u[(size_t)r * DINNER + d];
        const float* bm = xdbl + (size_t)r * 96 + DTRANK;
        const float* cm = bm + NSTATE;
        float du = dlt * uu;
        float y = 0.f;
        #pragma unroll
        for (int n = 0; n < NSTATE; n++) {
            float dA = __expf(dlt * Ad[n]);
            hs[n] = fmaf(dA, hs[n], du * bm[n]);
            y = fmaf(hs[n], cm[n], y);
        }
        float z = xz[(size_t)r * 4096 + DINNER + d];
        u[(size_t)r * DINNER + d] = (y + uu * Dd) * silu_f(z);
    }
}

// ---------------- Final: out = x + rs * (y2 * w) ----------------
__global__ __launch_bounds__(256) void final_kernel(
    const float* __restrict__ x, const float* __restrict__ y2,
    const float* __restrict__ w, const float* __restrict__ rs,
    float* __restrict__ out)
{
    size_t i = ((size_t)blockIdx.x * 256 + threadIdx.x) * 4;
    float r = rs[0];
    float4 xv = *(const float4*)(x + i);
    float4 yv = *(const float4*)(y2 + i);
    float4 wv = *(const float4*)(w + i);
    float4 o;
    o.x = xv.x + r * yv.x * wv.x;
    o.y = xv.y + r * yv.y * wv.y;
    o.z = xv.z + r * yv.z * wv.z;
    o.w = xv.w + r * yv.w * wv.w;
    *(float4*)(out + i) = o;
}

extern "C" void kernel_launch(void* const* d_in, const int* in_sizes, int n_in,
                              void* d_out, int out_size, void* d_ws, size_t ws_size,
                              hipStream_t stream)
{
    const float* x         = (const float*)d_in[0];
    const float* ln_g      = (const float*)d_in[1];
    const float* ln_b      = (const float*)d_in[2];
    const float* sq_w      = (const float*)d_in[3];
    const float* sq_b      = (const float*)d_in[4];
    const float* srw_w     = (const float*)d_in[5];
    const float* srw_b     = (const float*)d_in[6];
    const float* res_scale = (const float*)d_in[7];
    const float* in_proj_w = (const float*)d_in[8];
    const float* conv_w    = (const float*)d_in[9];
    const float* conv_b    = (const float*)d_in[10];
    const float* x_proj_w  = (const float*)d_in[11];
    const float* dt_w      = (const float*)d_in[12];
    const float* dt_b      = (const float*)d_in[13];
    const float* A_log     = (const float*)d_in[14];
    const float* Dp        = (const float*)d_in[15];
    const float* out_proj_w= (const float*)d_in[16];
    float* out = (float*)d_out;

    // workspace layout (162 MB total), with reuse:
    //   h0 (16MB) -> y2 ; h (16MB) -> P ; xz (64MB, delta overlaid on cols 0..2047)
    //   u (32MB) -> yz in-place ; xdbl (2MB) ; S (16MB) ; Hin (16MB) -> w
    char* ws = (char*)d_ws;
    float* h0   = (float*)(ws + 0);
    float* h    = (float*)(ws + ((size_t)16 << 20));
    float* xz   = (float*)(ws + ((size_t)32 << 20));
    float* u    = (float*)(ws + ((size_t)96 << 20));
    float* xdbl = (float*)(ws + ((size_t)128 << 20));
    float* S    = (float*)(ws + ((size_t)130 << 20));
    float* Hin  = (float*)(ws + ((size_t)146 << 20));
    float* P    = h;     // h dead after in_proj GEMM
    float* y2   = h0;    // h0 dead after spatial-query GEMM
    float* wbuf = Hin;   // Hin dead after phase C

    dim3 blk(256);

    // 1) LayerNorm
    ln_kernel<<<ROWS, blk, 0, stream>>>(x, ln_g, ln_b, h0);
    // 2) h = h0 + h0@sq_w + sq_b
    gemm_f32<0, true, true><<<dim3(8, 32), blk, 0, stream>>>(
        h0, sq_w, h, sq_b, h0, ROWS, DMODEL, DMODEL, DMODEL, DMODEL, DMODEL);
    // 3) xz = h @ in_proj_w   [4096, 4096]
    gemm_f32<0, false, false><<<dim3(32, 32), blk, 0, stream>>>(
        h, in_proj_w, xz, nullptr, nullptr, ROWS, 2 * DINNER, DMODEL, DMODEL, 2 * DINNER, 2 * DINNER);
    // 4) u = silu(causal_dwconv(xz[:, :2048]))
    conv_silu_kernel<<<(ROWS * DINNER) / 256, blk, 0, stream>>>(xz, conv_w, conv_b, u);
    // 5) xdbl = u @ x_proj_w   [4096, 96]
    gemm_f32<0, false, false><<<dim3(1, 32), blk, 0, stream>>>(
        u, x_proj_w, xdbl, nullptr, nullptr, ROWS, 96, DINNER, DINNER, 96, 96);
    // 6) delta = softplus(xdbl[:, :64] @ dt_w + dt_b), written over xz cols 0..2047 (ldc=4096)
    gemm_f32<1, true, false><<<dim3(16, 32), blk, 0, stream>>>(
        xdbl, dt_w, xz, dt_b, nullptr, ROWS, DINNER, DTRANK, 96, DINNER, 2 * DINNER);
    // 7-9) chunked scan
    scan_phaseA<<<dim3(DINNER / 256, NC, BATCH), blk, 0, stream>>>(xz, 2 * DINNER, u, xdbl, A_log, S, P);
    scan_phaseB<<<dim3((BATCH * DINNER) / 256), blk, 0, stream>>>(P, S, Hin);
    scan_phaseC<<<dim3(DINNER / 256, NC, BATCH), blk, 0, stream>>>(xz, 2 * DINNER, u, xdbl, A_log, Hin, Dp, xz);
    // 10) y2 = yz @ out_proj_w   [4096, 1024]
    gemm_f32<0, false, false><<<dim3(8, 32), blk, 0, stream>>>(
        u, out_proj_w, y2, nullptr, nullptr, ROWS, DMODEL, DINNER, DINNER, DMODEL, DMODEL);
    // 11) w = y2 @ srw_w + srw_b
    gemm_f32<0, true, false><<<dim3(8, 32), blk, 0, stream>>>(
        y2, srw_w, wbuf, srw_b, nullptr, ROWS, DMODEL, DMODEL, DMODEL, DMODEL, DMODEL);
    // 12) out = x + res_scale * (y2 * w)
    final_kernel<<<(ROWS * DMODEL) / (256 * 4), blk, 0, stream>>>(x, y2, wbuf, res_scale, out);
}

// Round 2
// 432.037 us; speedup vs baseline: 3.6495x; 3.6495x over previous
//
#include <hip/hip_runtime.h>
#include <math.h>

// Topoformer-Mamba block. Round 2: bf16 MFMA GEMMs (m97 structure), fp32 scan.
// B=2, L=2048, D_MODEL=1024, D_INNER=2048, N(state)=16, DT_RANK=64, d_conv=4.

#define DMODEL 1024
#define DINNER 2048
#define NSTATE 16
#define DTRANK 64
#define BATCH  2
#define SEQ    2048
#define ROWS   (BATCH*SEQ)     // 4096
#define NC     64              // scan chunks
#define TS     (SEQ/NC)        // 32 steps per chunk
#define LN_EPS 1e-5f

typedef unsigned short u16;
typedef __attribute__((ext_vector_type(8))) short bf16x8;
typedef __attribute__((ext_vector_type(4))) float f32x4;

__device__ __forceinline__ float silu_f(float x) { return x / (1.f + __expf(-x)); }

__device__ __forceinline__ u16 f2bf(float f) {
    union { float f; unsigned u; } v; v.f = f;
    unsigned r = v.u + 0x7fffu + ((v.u >> 16) & 1u);
    return (u16)(r >> 16);
}
__device__ __forceinline__ float bf2f(u16 h) {
    union { unsigned u; float f; } v; v.u = ((unsigned)h) << 16; return v.f;
}

__device__ __forceinline__ void gload_lds16(const u16* g, u16* l) {
    __builtin_amdgcn_global_load_lds(
        (const __attribute__((address_space(1))) unsigned int*)(g),
        (__attribute__((address_space(3))) unsigned int*)(static_cast<void*>(l)),
        16, 0, 0);
}

// ---------------- LayerNorm (one block per row), writes f32 + bf16 ----------------
__global__ __launch_bounds__(256) void ln_kernel(const float* __restrict__ x,
                                                 const float* __restrict__ g,
                                                 const float* __restrict__ bta,
                                                 float* __restrict__ out,
                                                 u16* __restrict__ outbf)
{
    int row = blockIdx.x;
    const float* xr = x + (size_t)row * DMODEL;
    float4 v = ((const float4*)xr)[threadIdx.x];
    float s  = v.x + v.y + v.z + v.w;
    float ss = v.x*v.x + v.y*v.y + v.z*v.z + v.w*v.w;
    #pragma unroll
    for (int off = 32; off; off >>= 1) { s += __shfl_down(s, off); ss += __shfl_down(ss, off); }
    __shared__ float s_s[4], s_ss[4];
    int lane = threadIdx.x & 63, w = threadIdx.x >> 6;
    if (lane == 0) { s_s[w] = s; s_ss[w] = ss; }
    __syncthreads();
    float ts = 0.f, tss = 0.f;
    #pragma unroll
    for (int i = 0; i < 4; i++) { ts += s_s[i]; tss += s_ss[i]; }
    float mu  = ts / (float)DMODEL;
    float var = tss / (float)DMODEL - mu * mu;
    float rstd = rsqrtf(var + LN_EPS);
    float4 gv = ((const float4*)g)[threadIdx.x];
    float4 bv = ((const float4*)bta)[threadIdx.x];
    float4 o;
    o.x = (v.x - mu) * rstd * gv.x + bv.x;
    o.y = (v.y - mu) * rstd * gv.y + bv.y;
    o.z = (v.z - mu) * rstd * gv.z + bv.z;
    o.w = (v.w - mu) * rstd * gv.w + bv.w;
    ((float4*)(out + (size_t)row * DMODEL))[threadIdx.x] = o;
    unsigned lo = (unsigned)f2bf(o.x) | ((unsigned)f2bf(o.y) << 16);
    unsigned hi = (unsigned)f2bf(o.z) | ((unsigned)f2bf(o.w) << 16);
    ((uint2*)(outbf + (size_t)row * DMODEL))[threadIdx.x] = make_uint2(lo, hi);
}

// ---------------- Transpose + fp32->bf16 convert: dst[c][r] = bf16(src[r][c]) ----------------
// src [R,C] f32; dst [Cpad,R] bf16 (rows >= C zero-filled). R%32==0; grid (Cpad/32, R/32), block (32,8).
__global__ __launch_bounds__(256) void transpose_bf16(const float* __restrict__ src,
                                                      u16* __restrict__ dst,
                                                      int R, int C)
{
    __shared__ float t[32][33];
    int c0 = blockIdx.x * 32, r0 = blockIdx.y * 32;
    int x = threadIdx.x, y = threadIdx.y;
    #pragma unroll
    for (int i = 0; i < 32; i += 8) {
        float v = 0.f;
        if (c0 + x < C) v = src[(size_t)(r0 + y + i) * C + c0 + x];
        t[y + i][x] = v;
    }
    __syncthreads();
    #pragma unroll
    for (int i = 0; i < 32; i += 8)
        dst[(size_t)(c0 + y + i) * R + r0 + x] = f2bf(t[x][y + i]);
}

// ---------------- bf16 MFMA GEMM: C = act(A@Bt^T [+bias] [+res]) ----------------
// A [M,K] bf16 (lda), Bt [N,K] bf16 (ldb=K). 128x128 tile, BK=32, 256 thr = 4 waves,
// each wave one 64x64 quadrant = 4x4 of 16x16x32 MFMA. C f32 (+optional bf16 mirror).
template<int ACT, bool HAS_BIAS, bool HAS_RES, bool WRITE_BF16>
__global__ __launch_bounds__(256) void gemm_bf16(
    const u16* __restrict__ A, const u16* __restrict__ Bt,
    float* __restrict__ C, u16* __restrict__ Cbf,
    const float* __restrict__ bias, const float* __restrict__ res,
    int K, int lda, int ldb, int ldc, int Nout)
{
    __shared__ __align__(16) u16 As[128 * 32];
    __shared__ __align__(16) u16 Bs[128 * 32];
    const int tid = threadIdx.x;
    const int wv = tid >> 6, ln = tid & 63;
    const int m0 = blockIdx.y * 128, n0 = blockIdx.x * 128;
    const int g = ln >> 4, r = ln & 15;
    const int wr = wv >> 1, wc = wv & 1;

    const u16* a_g0 = A + (size_t)(m0 + (tid >> 2)) * lda + (tid & 3) * 8;
    const u16* a_g1 = a_g0 + (size_t)64 * lda;
    const u16* b_g0 = Bt + (size_t)(n0 + (tid >> 2)) * ldb + (tid & 3) * 8;
    const u16* b_g1 = b_g0 + (size_t)64 * ldb;
    u16* a_l = As + wv * 512;   // hardware adds lane*16B; +2048 u16 for second 4KB half
    u16* b_l = Bs + wv * 512;

    f32x4 acc[4][4];
    #pragma unroll
    for (int i = 0; i < 4; i++)
        #pragma unroll
        for (int j = 0; j < 4; j++) acc[i][j] = (f32x4)0.f;

    for (int k0 = 0; k0 < K; k0 += 32) {
        __syncthreads();
        gload_lds16(a_g0 + k0, a_l);
        gload_lds16(a_g1 + k0, a_l + 2048);
        gload_lds16(b_g0 + k0, b_l);
        gload_lds16(b_g1 + k0, b_l + 2048);
        __syncthreads();
        bf16x8 av[4], bv[4];
        #pragma unroll
        for (int mi = 0; mi < 4; mi++)
            av[mi] = *(const bf16x8*)&As[(wr * 64 + mi * 16 + r) * 32 + g * 8];
        #pragma unroll
        for (int ni = 0; ni < 4; ni++)
            bv[ni] = *(const bf16x8*)&Bs[(wc * 64 + ni * 16 + r) * 32 + g * 8];
        #pragma unroll
        for (int mi = 0; mi < 4; mi++)
            #pragma unroll
            for (int ni = 0; ni < 4; ni++)
                acc[mi][ni] = __builtin_amdgcn_mfma_f32_16x16x32_bf16(av[mi], bv[ni], acc[mi][ni], 0, 0, 0);
    }

    // C/D layout (verified m89/m91): col = lane&15, row = (lane>>4)*4 + reg
    #pragma unroll
    for (int mi = 0; mi < 4; mi++) {
        int row0 = m0 + wr * 64 + mi * 16 + g * 4;
        #pragma unroll
        for (int ni = 0; ni < 4; ni++) {
            int col = n0 + wc * 64 + ni * 16 + r;
            if (col >= Nout) continue;
            float bb = HAS_BIAS ? bias[col] : 0.f;
            #pragma unroll
            for (int j = 0; j < 4; j++) {
                int row = row0 + j;
                float c = acc[mi][ni][j] + bb;
                if (HAS_RES) c += res[(size_t)row * ldc + col];
                if (ACT == 1) c = logf(1.f + __expf(c));  // softplus (args are ~-4.6, safe)
                C[(size_t)row * ldc + col] = c;
                if (WRITE_BF16) Cbf[(size_t)row * ldc + col] = f2bf(c);
            }
        }
    }
}

// ---------------- Causal depthwise conv (d_conv=4) + SiLU -> bf16 u ----------------
__global__ __launch_bounds__(256) void conv_silu_kernel(
    const float* __restrict__ xz, const float* __restrict__ w,
    const float* __restrict__ b, u16* __restrict__ u)
{
    size_t idx = (size_t)blockIdx.x * 256 + threadIdx.x;  // ROWS*DINNER
    int d = (int)(idx & (DINNER - 1));
    int r = (int)(idx >> 11);
    int t = r & (SEQ - 1);
    float4 wv = *(const float4*)(w + (size_t)d * 4);
    float acc = b[d];
    const float* wf = (const float*)&wv;
    #pragma unroll
    for (int j = 0; j < 4; j++) {
        int tt = t - 3 + j;
        if (tt >= 0)
            acc = fmaf(xz[(size_t)(r - 3 + j) * 4096 + d], wf[j], acc);
    }
    u[idx] = f2bf(silu_f(acc));
}

// ---------------- Chunked selective scan (fp32 state, bf16 u) ----------------
__global__ __launch_bounds__(256) void scan_phaseA(
    const float* __restrict__ delta, int ldd,
    const u16* __restrict__ u,
    const float* __restrict__ xdbl,   // [ROWS,96]; B at +64
    const float* __restrict__ A_log,
    float* __restrict__ S, float* __restrict__ P)
{
    int d = blockIdx.x * 256 + threadIdx.x;
    int c = blockIdx.y, b = blockIdx.z;
    float Ad[NSTATE];
    #pragma unroll
    for (int n = 0; n < NSTATE; n++) Ad[n] = -__expf(A_log[(size_t)d * NSTATE + n]);
    float hs[NSTATE], pr[NSTATE];
    #pragma unroll
    for (int n = 0; n < NSTATE; n++) { hs[n] = 0.f; pr[n] = 1.f; }
    int r0 = b * SEQ + c * TS;
    for (int t = 0; t < TS; t++) {
        int r = r0 + t;
        float dlt = delta[(size_t)r * ldd + d];
        float uu  = bf2f(u[(size_t)r * DINNER + d]);
        const float* bm = xdbl + (size_t)r * 96 + DTRANK;
        float du = dlt * uu;
        #pragma unroll
        for (int n = 0; n < NSTATE; n++) {
            float dA = __expf(dlt * Ad[n]);
            hs[n] = fmaf(dA, hs[n], du * bm[n]);
            pr[n] *= dA;
        }
    }
    size_t base = ((size_t)(b * NC + c) * DINNER + d) * NSTATE;
    #pragma unroll
    for (int n = 0; n < NSTATE; n += 4) {
        *(float4*)(S + base + n) = make_float4(hs[n], hs[n+1], hs[n+2], hs[n+3]);
        *(float4*)(P + base + n) = make_float4(pr[n], pr[n+1], pr[n+2], pr[n+3]);
    }
}

__global__ __launch_bounds__(256) void scan_phaseB(
    const float* __restrict__ P, const float* __restrict__ S, float* __restrict__ Hin)
{
    int idx = blockIdx.x * 256 + threadIdx.x;  // BATCH*DINNER
    int d = idx & (DINNER - 1);
    int b = idx >> 11;
    float h[NSTATE];
    #pragma unroll
    for (int n = 0; n < NSTATE; n++) h[n] = 0.f;
    for (int c = 0; c < NC; c++) {
        size_t base = ((size_t)(b * NC + c) * DINNER + d) * NSTATE;
        #pragma unroll
        for (int n = 0; n < NSTATE; n += 4)
            *(float4*)(Hin + base + n) = make_float4(h[n], h[n+1], h[n+2], h[n+3]);
        #pragma unroll
        for (int n = 0; n < NSTATE; n++)
            h[n] = fmaf(P[base + n], h[n], S[base + n]);
    }
}

// Phase C: replay with carry-in; y = (scan_y + u*D) * silu(z); write bf16 in-place over u.
__global__ __launch_bounds__(256) void scan_phaseC(
    const float* __restrict__ delta, int ldd,
    u16* __restrict__ u,              // in: u (bf16); out: yz (bf16, in-place)
    const float* __restrict__ xdbl,   // B at +64, C at +80
    const float* __restrict__ A_log,
    const float* __restrict__ Hin,
    const float* __restrict__ Dp,
    const float* __restrict__ xz)     // z at col 2048+d, ld 4096
{
    int d = blockIdx.x * 256 + threadIdx.x;
    int c = blockIdx.y, b = blockIdx.z;
    float Ad[NSTATE];
    #pragma unroll
    for (int n = 0; n < NSTATE; n++) Ad[n] = -__expf(A_log[(size_t)d * NSTATE + n]);
    float hs[NSTATE];
    size_t hbase = ((size_t)(b * NC + c) * DINNER + d) * NSTATE;
    #pragma unroll
    for (int n = 0; n < NSTATE; n++) hs[n] = Hin[hbase + n];
    float Dd = Dp[d];
    int r0 = b * SEQ + c * TS;
    for (int t = 0; t < TS; t++) {
        int r = r0 + t;
        float dlt = delta[(size_t)r * ldd + d];
        float uu  = bf2f(u[(size_t)r * DINNER + d]);
        const float* bm = xdbl + (size_t)r * 96 + DTRANK;
        const float* cm = bm + NSTATE;
        float du = dlt * uu;
        float y = 0.f;
        #pragma unroll
        for (int n = 0; n < NSTATE; n++) {
            float dA = __expf(dlt * Ad[n]);
            hs[n] = fmaf(dA, hs[n], du * bm[n]);
            y = fmaf(hs[n], cm[n], y);
        }
        float z = xz[(size_t)r * 4096 + DINNER + d];
        u[(size_t)r * DINNER + d] = f2bf((y + uu * Dd) * silu_f(z));
    }
}

// ---------------- Final: out = x + rs * (y2 * w) ----------------
__global__ __launch_bounds__(256) void final_kernel(
    const float* __restrict__ x, const float* __restrict__ y2,
    const float* __restrict__ w, const float* __restrict__ rs,
    float* __restrict__ out)
{
    size_t i = ((size_t)blockIdx.x * 256 + threadIdx.x) * 4;
    float r = rs[0];
    float4 xv = *(const float4*)(x + i);
    float4 yv = *(const float4*)(y2 + i);
    float4 wv = *(const float4*)(w + i);
    float4 o;
    o.x = xv.x + r * yv.x * wv.x;
    o.y = xv.y + r * yv.y * wv.y;
    o.z = xv.z + r * yv.z * wv.z;
    o.w = xv.w + r * yv.w * wv.w;
    *(float4*)(out + i) = o;
}

extern "C" void kernel_launch(void* const* d_in, const int* in_sizes, int n_in,
                              void* d_out, int out_size, void* d_ws, size_t ws_size,
                              hipStream_t stream)
{
    const float* x         = (const float*)d_in[0];
    const float* ln_g      = (const float*)d_in[1];
    const float* ln_b      = (const float*)d_in[2];
    const float* sq_w      = (const float*)d_in[3];
    const float* sq_b      = (const float*)d_in[4];
    const float* srw_w     = (const float*)d_in[5];
    const float* srw_b     = (const float*)d_in[6];
    const float* res_scale = (const float*)d_in[7];
    const float* in_proj_w = (const float*)d_in[8];
    const float* conv_w    = (const float*)d_in[9];
    const float* conv_b    = (const float*)d_in[10];
    const float* x_proj_w  = (const float*)d_in[11];
    const float* dt_w      = (const float*)d_in[12];
    const float* dt_b      = (const float*)d_in[13];
    const float* A_log     = (const float*)d_in[14];
    const float* Dp        = (const float*)d_in[15];
    const float* out_proj_w= (const float*)d_in[16];
    float* out = (float*)d_out;

    // workspace layout (~162 MB), with reuse:
    // A[0,16): h0 f32 -> y2 f32
    // B[16,32): h f32 -> P f32
    // C[32,96): xz f32 (delta overwrites cols 0..2047 after conv)
    // D[96,112): u bf16 -> yz bf16 (in place)
    // E[112,114): xdbl f32 (1.5MB) + xprojT bf16 (0.5MB slack)
    // F[114,130): h0_bf(8)+h_bf(8) -> xdbl_bf(0.75) -> S f32(16) -> y2_bf(8)
    // G[130,146): Hin f32 -> wbuf f32
    // H[146,162.25): sqT(2) srwT(2) inprojT(8) outprojT(4) dtT(0.25)
    char* ws = (char*)d_ws;
    float* h0      = (float*)(ws + 0);
    float* h       = (float*)(ws + ((size_t)16 << 20));
    float* xz      = (float*)(ws + ((size_t)32 << 20));
    u16*   u_bf    = (u16*)  (ws + ((size_t)96 << 20));
    float* xdbl    = (float*)(ws + ((size_t)112 << 20));
    u16*   xprojT  = (u16*)  (ws + ((size_t)112 << 20) + 1572864);
    u16*   h0_bf   = (u16*)  (ws + ((size_t)114 << 20));
    u16*   h_bf    = (u16*)  (ws + ((size_t)122 << 20));
    float* S       = (float*)(ws + ((size_t)114 << 20));
    float* Hin     = (float*)(ws + ((size_t)130 << 20));
    u16*   sqT     = (u16*)  (ws + ((size_t)146 << 20));
    u16*   srwT    = (u16*)  (ws + ((size_t)148 << 20));
    u16*   inprojT = (u16*)  (ws + ((size_t)150 << 20));
    u16*   outprojT= (u16*)  (ws + ((size_t)158 << 20));
    u16*   dtT     = (u16*)  (ws + ((size_t)162 << 20));
    float* P       = h;       // h dead after in_proj GEMM
    float* y2      = h0;      // h0 dead after sq GEMM
    float* wbuf    = Hin;     // Hin dead after phase C
    u16*   xdbl_bf = h0_bf;   // h0_bf dead after sq GEMM
    u16*   y2_bf   = h0_bf;   // S dead after phase B

    dim3 blk(256), tblk(32, 8);

    // 0) weight transpose-convert to bf16 [N,K]
    transpose_bf16<<<dim3(32, 32),  tblk, 0, stream>>>(sq_w,      sqT,      DMODEL, DMODEL);
    transpose_bf16<<<dim3(32, 32),  tblk, 0, stream>>>(srw_w,     srwT,     DMODEL, DMODEL);
    transpose_bf16<<<dim3(128, 32), tblk, 0, stream>>>(in_proj_w, inprojT,  DMODEL, 2 * DINNER);
    transpose_bf16<<<dim3(32, 64),  tblk, 0, stream>>>(out_proj_w,outprojT, DINNER, DMODEL);
    transpose_bf16<<<dim3(4, 64),   tblk, 0, stream>>>(x_proj_w,  xprojT,   DINNER, 96);   // pad to 128 rows
    transpose_bf16<<<dim3(64, 2),   tblk, 0, stream>>>(dt_w,      dtT,      DTRANK, DINNER);

    // 1) LayerNorm -> h0 f32 + h0_bf
    ln_kernel<<<ROWS, blk, 0, stream>>>(x, ln_g, ln_b, h0, h0_bf);
    // 2) h = h0 + h0@sq_w + sq_b   -> h f32 + h_bf
    gemm_bf16<0, true, true, true><<<dim3(8, 32), blk, 0, stream>>>(
        h0_bf, sqT, h, h_bf, sq_b, h0, DMODEL, DMODEL, DMODEL, DMODEL, DMODEL);
    // 3) xz = h @ in_proj_w   [4096, 4096] f32
    gemm_bf16<0, false, false, false><<<dim3(32, 32), blk, 0, stream>>>(
        h_bf, inprojT, xz, nullptr, nullptr, nullptr, DMODEL, DMODEL, DMODEL, 2 * DINNER, 2 * DINNER);
    // 4) u = silu(causal_dwconv(xz[:, :2048])) -> bf16
    conv_silu_kernel<<<(ROWS * DINNER) / 256, blk, 0, stream>>>(xz, conv_w, conv_b, u_bf);
    // 5) xdbl = u @ x_proj_w  [4096, 96] f32 + bf16 (N padded to 128, masked)
    gemm_bf16<0, false, false, true><<<dim3(1, 32), blk, 0, stream>>>(
        u_bf, xprojT, xdbl, xdbl_bf, nullptr, nullptr, DINNER, DINNER, DINNER, 96, 96);
    // 6) delta = softplus(xdbl[:, :64] @ dt_w + dt_b) -> xz cols 0..2047 (ldc=4096)
    gemm_bf16<1, true, false, false><<<dim3(16, 32), blk, 0, stream>>>(
        xdbl_bf, dtT, xz, nullptr, dt_b, nullptr, DTRANK, 96, DTRANK, 2 * DINNER, DINNER);
    // 7-9) chunked scan (fp32 state)
    scan_phaseA<<<dim3(DINNER / 256, NC, BATCH), blk, 0, stream>>>(xz, 2 * DINNER, u_bf, xdbl, A_log, S, P);
    scan_phaseB<<<dim3((BATCH * DINNER) / 256), blk, 0, stream>>>(P, S, Hin);
    scan_phaseC<<<dim3(DINNER / 256, NC, BATCH), blk, 0, stream>>>(xz, 2 * DINNER, u_bf, xdbl, A_log, Hin, Dp, xz);
    // 10) y2 = yz @ out_proj_w  [4096, 1024] f32 + bf16
    gemm_bf16<0, false, false, true><<<dim3(8, 32), blk, 0, stream>>>(
        u_bf, outprojT, y2, y2_bf, nullptr, nullptr, DINNER, DINNER, DINNER, DMODEL, DMODEL);
    // 11) w = y2 @ srw_w + srw_b
    gemm_bf16<0, true, false, false><<<dim3(8, 32), blk, 0, stream>>>(
        y2_bf, srwT, wbuf, nullptr, srw_b, nullptr, DMODEL, DMODEL, DMODEL, DMODEL, DMODEL);
    // 12) out = x + res_scale * (y2 * w)
    final_kernel<<<(ROWS * DMODEL) / (256 * 4), blk, 0, stream>>>(x, y2, wbuf, res_scale, out);
}

// Round 3
// 342.190 us; speedup vs baseline: 4.6078x; 1.2626x over previous
//
#include <hip/hip_runtime.h>
#include <math.h>

// Topoformer-Mamba block. Round 3: parallel phaseB, split-K x_proj, bf16 traffic diet.
// B=2, L=2048, D_MODEL=1024, D_INNER=2048, N(state)=16, DT_RANK=64, d_conv=4.

#define DMODEL 1024
#define DINNER 2048
#define NSTATE 16
#define DTRANK 64
#define BATCH  2
#define SEQ    2048
#define ROWS   (BATCH*SEQ)     // 4096
#define NC     64              // scan chunks
#define TS     (SEQ/NC)        // 32 steps per chunk
#define LN_EPS 1e-5f

typedef unsigned short u16;
typedef __attribute__((ext_vector_type(8))) short bf16x8;
typedef __attribute__((ext_vector_type(4))) float f32x4;

__device__ __forceinline__ float silu_f(float x) { return x / (1.f + __expf(-x)); }

__device__ __forceinline__ u16 f2bf(float f) {
    union { float f; unsigned u; } v; v.f = f;
    unsigned r = v.u + 0x7fffu + ((v.u >> 16) & 1u);
    return (u16)(r >> 16);
}
__device__ __forceinline__ float bf2f(u16 h) {
    union { unsigned u; float f; } v; v.u = ((unsigned)h) << 16; return v.f;
}

__device__ __forceinline__ void gload_lds16(const u16* g, u16* l) {
    __builtin_amdgcn_global_load_lds(
        (const __attribute__((address_space(1))) unsigned int*)(g),
        (__attribute__((address_space(3))) unsigned int*)(static_cast<void*>(l)),
        16, 0, 0);
}

// ---------------- LayerNorm (one block per row), writes f32 + bf16 ----------------
__global__ __launch_bounds__(256) void ln_kernel(const float* __restrict__ x,
                                                 const float* __restrict__ g,
                                                 const float* __restrict__ bta,
                                                 float* __restrict__ out,
                                                 u16* __restrict__ outbf)
{
    int row = blockIdx.x;
    const float* xr = x + (size_t)row * DMODEL;
    float4 v = ((const float4*)xr)[threadIdx.x];
    float s  = v.x + v.y + v.z + v.w;
    float ss = v.x*v.x + v.y*v.y + v.z*v.z + v.w*v.w;
    #pragma unroll
    for (int off = 32; off; off >>= 1) { s += __shfl_down(s, off); ss += __shfl_down(ss, off); }
    __shared__ float s_s[4], s_ss[4];
    int lane = threadIdx.x & 63, w = threadIdx.x >> 6;
    if (lane == 0) { s_s[w] = s; s_ss[w] = ss; }
    __syncthreads();
    float ts = 0.f, tss = 0.f;
    #pragma unroll
    for (int i = 0; i < 4; i++) { ts += s_s[i]; tss += s_ss[i]; }
    float mu  = ts / (float)DMODEL;
    float var = tss / (float)DMODEL - mu * mu;
    float rstd = rsqrtf(var + LN_EPS);
    float4 gv = ((const float4*)g)[threadIdx.x];
    float4 bv = ((const float4*)bta)[threadIdx.x];
    float4 o;
    o.x = (v.x - mu) * rstd * gv.x + bv.x;
    o.y = (v.y - mu) * rstd * gv.y + bv.y;
    o.z = (v.z - mu) * rstd * gv.z + bv.z;
    o.w = (v.w - mu) * rstd * gv.w + bv.w;
    ((float4*)(out + (size_t)row * DMODEL))[threadIdx.x] = o;
    unsigned lo = (unsigned)f2bf(o.x) | ((unsigned)f2bf(o.y) << 16);
    unsigned hi = (unsigned)f2bf(o.z) | ((unsigned)f2bf(o.w) << 16);
    ((uint2*)(outbf + (size_t)row * DMODEL))[threadIdx.x] = make_uint2(lo, hi);
}

// ---------------- Transpose + fp32->bf16 convert: dst[c][r] = bf16(src[r][c]) ----------------
// src [R,C] f32; dst [Cpad,R] bf16 (rows >= C zero-filled). grid (Cpad/32, R/32), block (32,8).
__global__ __launch_bounds__(256) void transpose_bf16(const float* __restrict__ src,
                                                      u16* __restrict__ dst,
                                                      int R, int C)
{
    __shared__ float t[32][33];
    int c0 = blockIdx.x * 32, r0 = blockIdx.y * 32;
    int x = threadIdx.x, y = threadIdx.y;
    #pragma unroll
    for (int i = 0; i < 32; i += 8) {
        float v = 0.f;
        if (c0 + x < C) v = src[(size_t)(r0 + y + i) * C + c0 + x];
        t[y + i][x] = v;
    }
    __syncthreads();
    #pragma unroll
    for (int i = 0; i < 32; i += 8)
        dst[(size_t)(c0 + y + i) * R + r0 + x] = f2bf(t[x][y + i]);
}

// ---------------- bf16 MFMA GEMM: out = act(A@Bt^T [+bias] [+res]) ----------------
// A [M,K] bf16 (lda), Bt [N,K] bf16 (ldb). 128x128 tile, BK=32, 256 thr = 4 waves,
// each wave one 64x64 quadrant = 4x4 of 16x16x32 MFMA.
// ACT: 0=none, 1=softplus, 2=silu on cols >= DINNER (fused z-gate for in_proj).
// splitK>0: blockIdx.z selects K-slice, C is partial slab array (stride ROWS*ldc).
template<int ACT, bool HAS_BIAS, bool HAS_RES, bool WRITE_BF16, bool WRITE_F32>
__global__ __launch_bounds__(256) void gemm_bf16(
    const u16* __restrict__ A, const u16* __restrict__ Bt,
    float* __restrict__ C, u16* __restrict__ Cbf,
    const float* __restrict__ bias, const float* __restrict__ res,
    int K, int lda, int ldb, int ldc, int Nout, int splitK)
{
    if (splitK) {
        int sp = blockIdx.z;
        A  += (size_t)sp * splitK;
        Bt += (size_t)sp * splitK;
        C  += (size_t)sp * ROWS * ldc;
        K = splitK;
    }
    __shared__ __align__(16) u16 As[128 * 32];
    __shared__ __align__(16) u16 Bs[128 * 32];
    const int tid = threadIdx.x;
    const int wv = tid >> 6, ln = tid & 63;
    const int m0 = blockIdx.y * 128, n0 = blockIdx.x * 128;
    const int g = ln >> 4, r = ln & 15;
    const int wr = wv >> 1, wc = wv & 1;

    const u16* a_g0 = A + (size_t)(m0 + (tid >> 2)) * lda + (tid & 3) * 8;
    const u16* a_g1 = a_g0 + (size_t)64 * lda;
    const u16* b_g0 = Bt + (size_t)(n0 + (tid >> 2)) * ldb + (tid & 3) * 8;
    const u16* b_g1 = b_g0 + (size_t)64 * ldb;
    u16* a_l = As + wv * 512;
    u16* b_l = Bs + wv * 512;

    f32x4 acc[4][4];
    #pragma unroll
    for (int i = 0; i < 4; i++)
        #pragma unroll
        for (int j = 0; j < 4; j++) acc[i][j] = (f32x4)0.f;

    for (int k0 = 0; k0 < K; k0 += 32) {
        __syncthreads();
        gload_lds16(a_g0 + k0, a_l);
        gload_lds16(a_g1 + k0, a_l + 2048);
        gload_lds16(b_g0 + k0, b_l);
        gload_lds16(b_g1 + k0, b_l + 2048);
        __syncthreads();
        bf16x8 av[4], bv[4];
        #pragma unroll
        for (int mi = 0; mi < 4; mi++)
            av[mi] = *(const bf16x8*)&As[(wr * 64 + mi * 16 + r) * 32 + g * 8];
        #pragma unroll
        for (int ni = 0; ni < 4; ni++)
            bv[ni] = *(const bf16x8*)&Bs[(wc * 64 + ni * 16 + r) * 32 + g * 8];
        #pragma unroll
        for (int mi = 0; mi < 4; mi++)
            #pragma unroll
            for (int ni = 0; ni < 4; ni++)
                acc[mi][ni] = __builtin_amdgcn_mfma_f32_16x16x32_bf16(av[mi], bv[ni], acc[mi][ni], 0, 0, 0);
    }

    // C/D layout (verified m89/m91): col = lane&15, row = (lane>>4)*4 + reg
    #pragma unroll
    for (int mi = 0; mi < 4; mi++) {
        int row0 = m0 + wr * 64 + mi * 16 + g * 4;
        #pragma unroll
        for (int ni = 0; ni < 4; ni++) {
            int col = n0 + wc * 64 + ni * 16 + r;
            if (col >= Nout) continue;
            float bb = HAS_BIAS ? bias[col] : 0.f;
            #pragma unroll
            for (int j = 0; j < 4; j++) {
                int row = row0 + j;
                float c = acc[mi][ni][j] + bb;
                if (HAS_RES) c += res[(size_t)row * ldc + col];
                if (ACT == 1) c = logf(1.f + __expf(c));       // softplus
                if (ACT == 2 && col >= DINNER) c = silu_f(c);  // z-gate
                if (WRITE_F32) C[(size_t)row * ldc + col] = c;
                if (WRITE_BF16) Cbf[(size_t)row * ldc + col] = f2bf(c);
            }
        }
    }
}

// ---------------- Reduce split-K partials for x_proj: xdbl = sum of 4 slabs ----------------
__global__ __launch_bounds__(256) void reduce_xproj(const float* __restrict__ part,
                                                    float* __restrict__ xdbl,
                                                    u16* __restrict__ xdbl_bf)
{
    int i = blockIdx.x * 256 + threadIdx.x;  // ROWS*96
    const int SL = ROWS * 96;
    float s = part[i] + part[i + SL] + part[i + 2 * SL] + part[i + 3 * SL];
    xdbl[i] = s;
    xdbl_bf[i] = f2bf(s);
}

// ---------------- Causal depthwise conv (d_conv=4) + SiLU -> bf16 u ----------------
// reads u_raw = xz_bf[:, 0:2048] (bf16, ld 4096)
__global__ __launch_bounds__(256) void conv_silu_kernel(
    const u16* __restrict__ xzbf, const float* __restrict__ w,
    const float* __restrict__ b, u16* __restrict__ u)
{
    size_t idx = (size_t)blockIdx.x * 256 + threadIdx.x;  // ROWS*DINNER
    int d = (int)(idx & (DINNER - 1));
    int r = (int)(idx >> 11);
    int t = r & (SEQ - 1);
    float4 wv = *(const float4*)(w + (size_t)d * 4);
    float acc = b[d];
    const float* wf = (const float*)&wv;
    #pragma unroll
    for (int j = 0; j < 4; j++) {
        int tt = t - 3 + j;
        if (tt >= 0)
            acc = fmaf(bf2f(xzbf[(size_t)(r - 3 + j) * 4096 + d]), wf[j], acc);
    }
    u[idx] = f2bf(silu_f(acc));
}

// ---------------- Chunked selective scan (fp32 state; bf16 delta/u/z) ----------------
__global__ __launch_bounds__(256) void scan_phaseA(
    const u16* __restrict__ delta,    // [ROWS, DINNER] bf16
    const u16* __restrict__ u,
    const float* __restrict__ xdbl,   // [ROWS,96]; B at +64
    const float* __restrict__ A_log,
    float* __restrict__ S, float* __restrict__ P)
{
    int d = blockIdx.x * 256 + threadIdx.x;
    int c = blockIdx.y, b = blockIdx.z;
    float Ad[NSTATE];
    #pragma unroll
    for (int n = 0; n < NSTATE; n++) Ad[n] = -__expf(A_log[(size_t)d * NSTATE + n]);
    float hs[NSTATE], pr[NSTATE];
    #pragma unroll
    for (int n = 0; n < NSTATE; n++) { hs[n] = 0.f; pr[n] = 1.f; }
    int r0 = b * SEQ + c * TS;
    for (int t = 0; t < TS; t++) {
        int r = r0 + t;
        float dlt = bf2f(delta[(size_t)r * DINNER + d]);
        float uu  = bf2f(u[(size_t)r * DINNER + d]);
        const float* bm = xdbl + (size_t)r * 96 + DTRANK;
        float du = dlt * uu;
        #pragma unroll
        for (int n = 0; n < NSTATE; n++) {
            float dA = __expf(dlt * Ad[n]);
            hs[n] = fmaf(dA, hs[n], du * bm[n]);
            pr[n] *= dA;
        }
    }
    size_t base = ((size_t)(b * NC + c) * DINNER + d) * NSTATE;
    #pragma unroll
    for (int n = 0; n < NSTATE; n += 4) {
        *(float4*)(S + base + n) = make_float4(hs[n], hs[n+1], hs[n+2], hs[n+3]);
        *(float4*)(P + base + n) = make_float4(pr[n], pr[n+1], pr[n+2], pr[n+3]);
    }
}

// Phase B: chunk combine, one thread per (b,d,n) — 65536 threads, coalesced.
__global__ __launch_bounds__(256) void scan_phaseB(
    const float* __restrict__ P, const float* __restrict__ S, float* __restrict__ Hin)
{
    int idx = blockIdx.x * 256 + threadIdx.x;   // BATCH*DINNER*NSTATE
    int n  = idx & (NSTATE - 1);
    int dd = (idx >> 4) & (DINNER - 1);
    int b  = idx >> 15;
    const size_t stride = (size_t)DINNER * NSTATE;
    size_t base = ((size_t)b * NC * DINNER + dd) * NSTATE + n;
    float h = 0.f;
    #pragma unroll 8
    for (int c = 0; c < NC; c++) {
        size_t off = base + (size_t)c * stride;
        float p = P[off];
        float s = S[off];
        Hin[off] = h;
        h = fmaf(p, h, s);
    }
}

// Phase C: replay with carry-in; y = (scan_y + u*D) * silu(z); write bf16 in-place over u.
__global__ __launch_bounds__(256) void scan_phaseC(
    const u16* __restrict__ delta,
    u16* __restrict__ u,              // in: u (bf16); out: yz (bf16, in-place)
    const float* __restrict__ xdbl,   // B at +64, C at +80
    const float* __restrict__ A_log,
    const float* __restrict__ Hin,
    const float* __restrict__ Dp,
    const u16* __restrict__ xzbf)     // silu(z) at col 2048+d, ld 4096 (pre-gated in GEMM)
{
    int d = blockIdx.x * 256 + threadIdx.x;
    int c = blockIdx.y, b = blockIdx.z;
    float Ad[NSTATE];
    #pragma unroll
    for (int n = 0; n < NSTATE; n++) Ad[n] = -__expf(A_log[(size_t)d * NSTATE + n]);
    float hs[NSTATE];
    size_t hbase = ((size_t)(b * NC + c) * DINNER + d) * NSTATE;
    #pragma unroll
    for (int n = 0; n < NSTATE; n++) hs[n] = Hin[hbase + n];
    float Dd = Dp[d];
    int r0 = b * SEQ + c * TS;
    for (int t = 0; t < TS; t++) {
        int r = r0 + t;
        float dlt = bf2f(delta[(size_t)r * DINNER + d]);
        float uu  = bf2f(u[(size_t)r * DINNER + d]);
        const float* bm = xdbl + (size_t)r * 96 + DTRANK;
        const float* cm = bm + NSTATE;
        float du = dlt * uu;
        float y = 0.f;
        #pragma unroll
        for (int n = 0; n < NSTATE; n++) {
            float dA = __expf(dlt * Ad[n]);
            hs[n] = fmaf(dA, hs[n], du * bm[n]);
            y = fmaf(hs[n], cm[n], y);
        }
        float sz = bf2f(xzbf[(size_t)r * 4096 + DINNER + d]);  // already silu'd
        u[(size_t)r * DINNER + d] = f2bf((y + uu * Dd) * sz);
    }
}

// ---------------- Final: out = x + rs * (y2 * w) ----------------
__global__ __launch_bounds__(256) void final_kernel(
    const float* __restrict__ x, const float* __restrict__ y2,
    const float* __restrict__ w, const float* __restrict__ rs,
    float* __restrict__ out)
{
    size_t i = ((size_t)blockIdx.x * 256 + threadIdx.x) * 4;
    float r = rs[0];
    float4 xv = *(const float4*)(x + i);
    float4 yv = *(const float4*)(y2 + i);
    float4 wv = *(const float4*)(w + i);
    float4 o;
    o.x = xv.x + r * yv.x * wv.x;
    o.y = xv.y + r * yv.y * wv.y;
    o.z = xv.z + r * yv.z * wv.z;
    o.w = xv.w + r * yv.w * wv.w;
    *(float4*)(out + i) = o;
}

extern "C" void kernel_launch(void* const* d_in, const int* in_sizes, int n_in,
                              void* d_out, int out_size, void* d_ws, size_t ws_size,
                              hipStream_t stream)
{
    const float* x         = (const float*)d_in[0];
    const float* ln_g      = (const float*)d_in[1];
    const float* ln_b      = (const float*)d_in[2];
    const float* sq_w      = (const float*)d_in[3];
    const float* sq_b      = (const float*)d_in[4];
    const float* srw_w     = (const float*)d_in[5];
    const float* srw_b     = (const float*)d_in[6];
    const float* res_scale = (const float*)d_in[7];
    const float* in_proj_w = (const float*)d_in[8];
    const float* conv_w    = (const float*)d_in[9];
    const float* conv_b    = (const float*)d_in[10];
    const float* x_proj_w  = (const float*)d_in[11];
    const float* dt_w      = (const float*)d_in[12];
    const float* dt_b      = (const float*)d_in[13];
    const float* A_log     = (const float*)d_in[14];
    const float* Dp        = (const float*)d_in[15];
    const float* out_proj_w= (const float*)d_in[16];
    float* out = (float*)d_out;

    // workspace layout (MB offsets), lifetime-based reuse:
    //  0-16 : h0 f32 (steps 1-2) -> delta_bf 8MB (6-9) -> y2 f32 (10-12)
    // 16-32 : xpart 6MB (5) -> P f32 (7-8)
    // 32-64 : xz_bf bf16 (3-9; u_raw cols 0..2047, silu(z) cols 2048..4095)
    // 64-80 : u_bf -> yz bf16 in place
    // 80-82 : xdbl f32 (1.5MB)
    // 82-83 : xprojT bf16 (0.5MB)
    // 83-91 : h0_bf (1-2) -> xdbl_bf 0.75MB (5-6)
    // 91-99 : h_bf (2-3)
    // 99-115: S f32 (7-8) -> y2_bf 8MB (10-11)
    // 115-131: Hin f32 (8-9) -> wbuf f32 (11-12)
    // 131-147.25: weight transposes (whole call)
    char* ws = (char*)d_ws;
    float* h0      = (float*)(ws + 0);
    u16*   delta_bf= (u16*)  (ws + 0);
    float* y2      = (float*)(ws + 0);
    float* xpart   = (float*)(ws + ((size_t)16 << 20));
    float* P       = (float*)(ws + ((size_t)16 << 20));
    u16*   xz_bf   = (u16*)  (ws + ((size_t)32 << 20));
    u16*   u_bf    = (u16*)  (ws + ((size_t)64 << 20));
    float* xdbl    = (float*)(ws + ((size_t)80 << 20));
    u16*   xprojT  = (u16*)  (ws + ((size_t)82 << 20));
    u16*   h0_bf   = (u16*)  (ws + ((size_t)83 << 20));
    u16*   xdbl_bf = (u16*)  (ws + ((size_t)83 << 20));
    u16*   h_bf    = (u16*)  (ws + ((size_t)91 << 20));
    float* S       = (float*)(ws + ((size_t)99 << 20));
    u16*   y2_bf   = (u16*)  (ws + ((size_t)99 << 20));
    float* Hin     = (float*)(ws + ((size_t)115 << 20));
    float* wbuf    = (float*)(ws + ((size_t)115 << 20));
    u16*   sqT     = (u16*)  (ws + ((size_t)131 << 20));
    u16*   srwT    = (u16*)  (ws + ((size_t)133 << 20));
    u16*   inprojT = (u16*)  (ws + ((size_t)135 << 20));
    u16*   outprojT= (u16*)  (ws + ((size_t)143 << 20));
    u16*   dtT     = (u16*)  (ws + ((size_t)147 << 20));

    dim3 blk(256), tblk(32, 8);

    // 0) weight transpose-convert to bf16 [N,K]
    transpose_bf16<<<dim3(32, 32),  tblk, 0, stream>>>(sq_w,      sqT,      DMODEL, DMODEL);
    transpose_bf16<<<dim3(32, 32),  tblk, 0, stream>>>(srw_w,     srwT,     DMODEL, DMODEL);
    transpose_bf16<<<dim3(128, 32), tblk, 0, stream>>>(in_proj_w, inprojT,  DMODEL, 2 * DINNER);
    transpose_bf16<<<dim3(32, 64),  tblk, 0, stream>>>(out_proj_w,outprojT, DINNER, DMODEL);
    transpose_bf16<<<dim3(4, 64),   tblk, 0, stream>>>(x_proj_w,  xprojT,   DINNER, 96);   // pad 96->128 rows
    transpose_bf16<<<dim3(64, 2),   tblk, 0, stream>>>(dt_w,      dtT,      DTRANK, DINNER);

    // 1) LayerNorm -> h0 f32 + h0_bf
    ln_kernel<<<ROWS, blk, 0, stream>>>(x, ln_g, ln_b, h0, h0_bf);
    // 2) h_bf = bf16(h0 + h0@sq_w + sq_b)
    gemm_bf16<0, true, true, true, false><<<dim3(8, 32), blk, 0, stream>>>(
        h0_bf, sqT, nullptr, h_bf, sq_b, h0, DMODEL, DMODEL, DMODEL, DMODEL, DMODEL, 0);
    // 3) xz_bf = bf16(h @ in_proj_w), silu fused onto z-half (cols >= 2048)
    gemm_bf16<2, false, false, true, false><<<dim3(32, 32), blk, 0, stream>>>(
        h_bf, inprojT, nullptr, xz_bf, nullptr, nullptr, DMODEL, DMODEL, DMODEL, 2 * DINNER, 2 * DINNER, 0);
    // 4) u_bf = bf16(silu(causal_dwconv(xz_bf[:, :2048])))
    conv_silu_kernel<<<(ROWS * DINNER) / 256, blk, 0, stream>>>(xz_bf, conv_w, conv_b, u_bf);
    // 5) x_proj split-K=4: partials -> xpart
    gemm_bf16<0, false, false, false, true><<<dim3(1, 32, 4), blk, 0, stream>>>(
        u_bf, xprojT, xpart, nullptr, nullptr, nullptr, DINNER, DINNER, DINNER, 96, 96, DINNER / 4);
    reduce_xproj<<<(ROWS * 96) / 256, blk, 0, stream>>>(xpart, xdbl, xdbl_bf);
    // 6) delta_bf = bf16(softplus(xdbl[:, :64] @ dt_w + dt_b))
    gemm_bf16<1, true, false, true, false><<<dim3(16, 32), blk, 0, stream>>>(
        xdbl_bf, dtT, nullptr, delta_bf, dt_b, nullptr, DTRANK, 96, DTRANK, DINNER, DINNER, 0);
    // 7-9) chunked scan (fp32 state)
    scan_phaseA<<<dim3(DINNER / 256, NC, BATCH), blk, 0, stream>>>(delta_bf, u_bf, xdbl, A_log, S, P);
    scan_phaseB<<<dim3((BATCH * DINNER * NSTATE) / 256), blk, 0, stream>>>(P, S, Hin);
    scan_phaseC<<<dim3(DINNER / 256, NC, BATCH), blk, 0, stream>>>(delta_bf, u_bf, xdbl, A_log, Hin, Dp, xz_bf);
    // 10) y2 = yz @ out_proj_w  (f32 + bf16)
    gemm_bf16<0, false, false, true, true><<<dim3(8, 32), blk, 0, stream>>>(
        u_bf, outprojT, y2, y2_bf, nullptr, nullptr, DINNER, DINNER, DINNER, DMODEL, DMODEL, 0);
    // 11) wbuf = y2 @ srw_w + srw_b
    gemm_bf16<0, true, false, false, true><<<dim3(8, 32), blk, 0, stream>>>(
        y2_bf, srwT, wbuf, nullptr, srw_b, nullptr, DMODEL, DMODEL, DMODEL, DMODEL, DMODEL, 0);
    // 12) out = x + res_scale * (y2 * wbuf)
    final_kernel<<<(ROWS * DMODEL) / (256 * 4), blk, 0, stream>>>(x, y2, wbuf, res_scale, out);
}

// Round 4
// 337.003 us; speedup vs baseline: 4.6787x; 1.0154x over previous
//
#include <hip/hip_runtime.h>
#include <math.h>

// Topoformer-Mamba block. Round 4: 256^2 2-phase dbuf in_proj GEMM, scan traffic diet.
// B=2, L=2048, D_MODEL=1024, D_INNER=2048, N(state)=16, DT_RANK=64, d_conv=4.

#define DMODEL 1024
#define DINNER 2048
#define NSTATE 16
#define DTRANK 64
#define BATCH  2
#define SEQ    2048
#define ROWS   (BATCH*SEQ)     // 4096
#define NC     32              // scan chunks
#define TS     (SEQ/NC)        // 64 steps per chunk
#define LN_EPS 1e-5f

typedef unsigned short u16;
typedef __attribute__((ext_vector_type(8))) short bf16x8;
typedef __attribute__((ext_vector_type(4))) float f32x4;

__device__ __forceinline__ float silu_f(float x) { return x / (1.f + __expf(-x)); }

__device__ __forceinline__ u16 f2bf(float f) {
    union { float f; unsigned u; } v; v.f = f;
    unsigned r = v.u + 0x7fffu + ((v.u >> 16) & 1u);
    return (u16)(r >> 16);
}
__device__ __forceinline__ float bf2f(u16 h) {
    union { unsigned u; float f; } v; v.u = ((unsigned)h) << 16; return v.f;
}

__device__ __forceinline__ void gload_lds16(const u16* g, u16* l) {
    __builtin_amdgcn_global_load_lds(
        (const __attribute__((address_space(1))) unsigned int*)(g),
        (__attribute__((address_space(3))) unsigned int*)(static_cast<void*>(l)),
        16, 0, 0);
}

// ---------------- LayerNorm (one block per row), writes f32 + bf16 ----------------
__global__ __launch_bounds__(256) void ln_kernel(const float* __restrict__ x,
                                                 const float* __restrict__ g,
                                                 const float* __restrict__ bta,
                                                 float* __restrict__ out,
                                                 u16* __restrict__ outbf)
{
    int row = blockIdx.x;
    const float* xr = x + (size_t)row * DMODEL;
    float4 v = ((const float4*)xr)[threadIdx.x];
    float s  = v.x + v.y + v.z + v.w;
    float ss = v.x*v.x + v.y*v.y + v.z*v.z + v.w*v.w;
    #pragma unroll
    for (int off = 32; off; off >>= 1) { s += __shfl_down(s, off); ss += __shfl_down(ss, off); }
    __shared__ float s_s[4], s_ss[4];
    int lane = threadIdx.x & 63, w = threadIdx.x >> 6;
    if (lane == 0) { s_s[w] = s; s_ss[w] = ss; }
    __syncthreads();
    float ts = 0.f, tss = 0.f;
    #pragma unroll
    for (int i = 0; i < 4; i++) { ts += s_s[i]; tss += s_ss[i]; }
    float mu  = ts / (float)DMODEL;
    float var = tss / (float)DMODEL - mu * mu;
    float rstd = rsqrtf(var + LN_EPS);
    float4 gv = ((const float4*)g)[threadIdx.x];
    float4 bv = ((const float4*)bta)[threadIdx.x];
    float4 o;
    o.x = (v.x - mu) * rstd * gv.x + bv.x;
    o.y = (v.y - mu) * rstd * gv.y + bv.y;
    o.z = (v.z - mu) * rstd * gv.z + bv.z;
    o.w = (v.w - mu) * rstd * gv.w + bv.w;
    ((float4*)(out + (size_t)row * DMODEL))[threadIdx.x] = o;
    unsigned lo = (unsigned)f2bf(o.x) | ((unsigned)f2bf(o.y) << 16);
    unsigned hi = (unsigned)f2bf(o.z) | ((unsigned)f2bf(o.w) << 16);
    ((uint2*)(outbf + (size_t)row * DMODEL))[threadIdx.x] = make_uint2(lo, hi);
}

// ---------------- Transpose + fp32->bf16 convert: dst[c][r] = bf16(src[r][c]) ----------------
__global__ __launch_bounds__(256) void transpose_bf16(const float* __restrict__ src,
                                                      u16* __restrict__ dst,
                                                      int R, int C)
{
    __shared__ float t[32][33];
    int c0 = blockIdx.x * 32, r0 = blockIdx.y * 32;
    int x = threadIdx.x, y = threadIdx.y;
    #pragma unroll
    for (int i = 0; i < 32; i += 8) {
        float v = 0.f;
        if (c0 + x < C) v = src[(size_t)(r0 + y + i) * C + c0 + x];
        t[y + i][x] = v;
    }
    __syncthreads();
    #pragma unroll
    for (int i = 0; i < 32; i += 8)
        dst[(size_t)(c0 + y + i) * R + r0 + x] = f2bf(t[x][y + i]);
}

// ---------------- 128^2 bf16 MFMA GEMM (m97 structure) ----------------
// ACT: 0=none, 1=softplus. splitK>0: blockIdx.z selects K-slice, C partial slabs.
template<int ACT, bool HAS_BIAS, bool HAS_RES, bool WRITE_BF16, bool WRITE_F32>
__global__ __launch_bounds__(256) void gemm_bf16(
    const u16* __restrict__ A, const u16* __restrict__ Bt,
    float* __restrict__ C, u16* __restrict__ Cbf,
    const float* __restrict__ bias, const float* __restrict__ res,
    int K, int lda, int ldb, int ldc, int Nout, int splitK)
{
    if (splitK) {
        int sp = blockIdx.z;
        A  += (size_t)sp * splitK;
        Bt += (size_t)sp * splitK;
        C  += (size_t)sp * ROWS * ldc;
        K = splitK;
    }
    __shared__ __align__(16) u16 As[128 * 32];
    __shared__ __align__(16) u16 Bs[128 * 32];
    const int tid = threadIdx.x;
    const int wv = tid >> 6, ln = tid & 63;
    const int m0 = blockIdx.y * 128, n0 = blockIdx.x * 128;
    const int g = ln >> 4, r = ln & 15;
    const int wr = wv >> 1, wc = wv & 1;

    const u16* a_g0 = A + (size_t)(m0 + (tid >> 2)) * lda + (tid & 3) * 8;
    const u16* a_g1 = a_g0 + (size_t)64 * lda;
    const u16* b_g0 = Bt + (size_t)(n0 + (tid >> 2)) * ldb + (tid & 3) * 8;
    const u16* b_g1 = b_g0 + (size_t)64 * ldb;
    u16* a_l = As + wv * 512;
    u16* b_l = Bs + wv * 512;

    f32x4 acc[4][4];
    #pragma unroll
    for (int i = 0; i < 4; i++)
        #pragma unroll
        for (int j = 0; j < 4; j++) acc[i][j] = (f32x4)0.f;

    for (int k0 = 0; k0 < K; k0 += 32) {
        __syncthreads();
        gload_lds16(a_g0 + k0, a_l);
        gload_lds16(a_g1 + k0, a_l + 2048);
        gload_lds16(b_g0 + k0, b_l);
        gload_lds16(b_g1 + k0, b_l + 2048);
        __syncthreads();
        bf16x8 av[4], bv[4];
        #pragma unroll
        for (int mi = 0; mi < 4; mi++)
            av[mi] = *(const bf16x8*)&As[(wr * 64 + mi * 16 + r) * 32 + g * 8];
        #pragma unroll
        for (int ni = 0; ni < 4; ni++)
            bv[ni] = *(const bf16x8*)&Bs[(wc * 64 + ni * 16 + r) * 32 + g * 8];
        #pragma unroll
        for (int mi = 0; mi < 4; mi++)
            #pragma unroll
            for (int ni = 0; ni < 4; ni++)
                acc[mi][ni] = __builtin_amdgcn_mfma_f32_16x16x32_bf16(av[mi], bv[ni], acc[mi][ni], 0, 0, 0);
    }

    // C/D layout (verified m89/m91): col = lane&15, row = (lane>>4)*4 + reg
    #pragma unroll
    for (int mi = 0; mi < 4; mi++) {
        int row0 = m0 + wr * 64 + mi * 16 + g * 4;
        #pragma unroll
        for (int ni = 0; ni < 4; ni++) {
            int col = n0 + wc * 64 + ni * 16 + r;
            if (col >= Nout) continue;
            float bb = HAS_BIAS ? bias[col] : 0.f;
            #pragma unroll
            for (int j = 0; j < 4; j++) {
                int row = row0 + j;
                float c = acc[mi][ni][j] + bb;
                if (HAS_RES) c += res[(size_t)row * ldc + col];
                if (ACT == 1) c = logf(1.f + __expf(c));       // softplus
                if (WRITE_F32) C[(size_t)row * ldc + col] = c;
                if (WRITE_BF16) Cbf[(size_t)row * ldc + col] = f2bf(c);
            }
        }
    }
}

// ---------------- 256^2 2-phase double-buffered bf16 GEMM (in_proj) ----------------
// BM=BN=256, BK=32, 512 thr = 8 waves (2M x 4N), per-wave 128x64 = 8x4 MFMA frags.
// LDS 64 KB: 2 bufs x (A 16KB + B 16KB). XOR seg-swizzle (both sides, rule #21):
// LDS(row,seg) holds global (row, seg ^ ((row>>1)&3)); reads apply the same XOR.
// Epilogue: bf16 out; silu on cols >= DINNER when ZSILU (block-uniform, BN|2048).
__device__ __forceinline__ void stage256(const u16* __restrict__ A, const u16* __restrict__ Bt,
                                         int m0, int n0, int lda, int ldb, int k0,
                                         u16* As, u16* Bs, int tid)
{
    #pragma unroll
    for (int p = 0; p < 2; p++) {
        int idx = p * 512 + tid;
        int row = idx >> 2, seg = idx & 3;
        int sseg = seg ^ ((row >> 1) & 3);
        gload_lds16(A  + (size_t)(m0 + row) * lda + k0 + sseg * 8, As + idx * 8);
        gload_lds16(Bt + (size_t)(n0 + row) * ldb + k0 + sseg * 8, Bs + idx * 8);
    }
}

template<bool ZSILU>
__global__ __launch_bounds__(512, 2) void gemm256_bf16(
    const u16* __restrict__ A, const u16* __restrict__ Bt, u16* __restrict__ Cbf,
    int K, int lda, int ldb, int ldc)
{
    __shared__ __align__(16) u16 As[2][8192];
    __shared__ __align__(16) u16 Bs[2][8192];
    const int tid = threadIdx.x;
    const int wv = tid >> 6, ln = tid & 63;
    const int g = ln >> 4, r = ln & 15;
    const int wr = wv >> 2, wc = wv & 3;
    const int m0 = blockIdx.y * 256, n0 = blockIdx.x * 256;

    f32x4 acc[8][4];
    #pragma unroll
    for (int i = 0; i < 8; i++)
        #pragma unroll
        for (int j = 0; j < 4; j++) acc[i][j] = (f32x4)0.f;

    stage256(A, Bt, m0, n0, lda, ldb, 0, As[0], Bs[0], tid);
    __syncthreads();   // prologue: full drain (compiler emits vmcnt(0) before barrier)

    const int nt = K >> 5;
    for (int t = 0; t < nt; ++t) {
        const int cur = t & 1;
        if (t + 1 < nt)
            stage256(A, Bt, m0, n0, lda, ldb, (t + 1) << 5, As[cur ^ 1], Bs[cur ^ 1], tid);
        bf16x8 av[8], bv[4];
        #pragma unroll
        for (int mi = 0; mi < 8; mi++) {
            int arow = wr * 128 + mi * 16 + r;
            av[mi] = *(const bf16x8*)&As[cur][arow * 32 + ((g ^ ((arow >> 1) & 3)) << 3)];
        }
        #pragma unroll
        for (int ni = 0; ni < 4; ni++) {
            int brow = wc * 64 + ni * 16 + r;
            bv[ni] = *(const bf16x8*)&Bs[cur][brow * 32 + ((g ^ ((brow >> 1) & 3)) << 3)];
        }
        #pragma unroll
        for (int mi = 0; mi < 8; mi++)
            #pragma unroll
            for (int ni = 0; ni < 4; ni++)
                acc[mi][ni] = __builtin_amdgcn_mfma_f32_16x16x32_bf16(av[mi], bv[ni], acc[mi][ni], 0, 0, 0);
        if (t + 1 < nt) {
            // counted-distance drain: waits the 4 loads issued at loop top,
            // ~ (12 ds_read + 32 MFMA) after issue. One drain per K-tile.
            asm volatile("s_waitcnt vmcnt(0)" ::: "memory");
            __builtin_amdgcn_sched_barrier(0);
            __builtin_amdgcn_s_barrier();
        }
    }

    const bool isz = ZSILU && (n0 >= DINNER);
    #pragma unroll
    for (int mi = 0; mi < 8; mi++) {
        int row0 = m0 + wr * 128 + mi * 16 + g * 4;
        #pragma unroll
        for (int ni = 0; ni < 4; ni++) {
            int col = n0 + wc * 64 + ni * 16 + r;
            #pragma unroll
            for (int j = 0; j < 4; j++) {
                float c = acc[mi][ni][j];
                if (isz) c = silu_f(c);
                Cbf[(size_t)(row0 + j) * ldc + col] = f2bf(c);
            }
        }
    }
}

// ---------------- Reduce split-K partials for x_proj ----------------
__global__ __launch_bounds__(256) void reduce_xproj(const float* __restrict__ part,
                                                    float* __restrict__ xdbl,
                                                    u16* __restrict__ xdbl_bf)
{
    int i = blockIdx.x * 256 + threadIdx.x;  // ROWS*96
    const int SL = ROWS * 96;
    float s = part[i] + part[i + SL] + part[i + 2 * SL] + part[i + 3 * SL];
    xdbl[i] = s;
    xdbl_bf[i] = f2bf(s);
}

// ---------------- Causal depthwise conv (d_conv=4) + SiLU -> bf16 u ----------------
__global__ __launch_bounds__(256) void conv_silu_kernel(
    const u16* __restrict__ xzbf, const float* __restrict__ w,
    const float* __restrict__ b, u16* __restrict__ u)
{
    size_t idx = (size_t)blockIdx.x * 256 + threadIdx.x;  // ROWS*DINNER
    int d = (int)(idx & (DINNER - 1));
    int r = (int)(idx >> 11);
    int t = r & (SEQ - 1);
    float4 wv = *(const float4*)(w + (size_t)d * 4);
    float acc = b[d];
    const float* wf = (const float*)&wv;
    #pragma unroll
    for (int j = 0; j < 4; j++) {
        int tt = t - 3 + j;
        if (tt >= 0)
            acc = fmaf(bf2f(xzbf[(size_t)(r - 3 + j) * 4096 + d]), wf[j], acc);
    }
    u[idx] = f2bf(silu_f(acc));
}

// ---------------- Chunked selective scan (fp32 state; bf16 delta/u/z) ----------------
// Phase A: local scan from 0; store final local state S and per-chunk sum of delta
// (decay product over chunk = exp(Ad[n] * sumdelta), recomputed in phase B).
__global__ __launch_bounds__(256) void scan_phaseA(
    const u16* __restrict__ delta,    // [ROWS, DINNER] bf16
    const u16* __restrict__ u,
    const float* __restrict__ xdbl,   // [ROWS,96]; B at +64
    const float* __restrict__ A_log,
    float* __restrict__ S, float* __restrict__ sumdlt)
{
    int d = blockIdx.x * 256 + threadIdx.x;
    int c = blockIdx.y, b = blockIdx.z;
    float Ad[NSTATE];
    #pragma unroll
    for (int n = 0; n < NSTATE; n++) Ad[n] = -__expf(A_log[(size_t)d * NSTATE + n]);
    float hs[NSTATE];
    #pragma unroll
    for (int n = 0; n < NSTATE; n++) hs[n] = 0.f;
    float sd = 0.f;
    int r0 = b * SEQ + c * TS;
    for (int t = 0; t < TS; t++) {
        int r = r0 + t;
        float dlt = bf2f(delta[(size_t)r * DINNER + d]);
        float uu  = bf2f(u[(size_t)r * DINNER + d]);
        const float* bm = xdbl + (size_t)r * 96 + DTRANK;
        float du = dlt * uu;
        sd += dlt;
        #pragma unroll
        for (int n = 0; n < NSTATE; n++) {
            float dA = __expf(dlt * Ad[n]);
            hs[n] = fmaf(dA, hs[n], du * bm[n]);
        }
    }
    size_t base = ((size_t)(b * NC + c) * DINNER + d) * NSTATE;
    #pragma unroll
    for (int n = 0; n < NSTATE; n += 4)
        *(float4*)(S + base + n) = make_float4(hs[n], hs[n+1], hs[n+2], hs[n+3]);
    sumdlt[(size_t)(b * NC + c) * DINNER + d] = sd;
}

// Phase B: chunk combine, one thread per (b,d,n); decay recomputed from sumdelta.
__global__ __launch_bounds__(256) void scan_phaseB(
    const float* __restrict__ S, const float* __restrict__ sumdlt,
    const float* __restrict__ A_log, float* __restrict__ Hin)
{
    int idx = blockIdx.x * 256 + threadIdx.x;   // BATCH*DINNER*NSTATE
    int b  = idx >> 15;
    int dn = idx & (DINNER * NSTATE - 1);       // d*16+n, coalesced A_log read
    float Ad = -__expf(A_log[dn]);
    int d = dn >> 4;
    const size_t stride = (size_t)DINNER * NSTATE;
    size_t base  = (size_t)b * NC * stride + dn;
    size_t sbase = (size_t)b * NC * DINNER + d;
    float h = 0.f;
    for (int c = 0; c < NC; c++) {
        size_t off = base + (size_t)c * stride;
        float p = __expf(Ad * sumdlt[sbase + (size_t)c * DINNER]);
        float s = S[off];
        Hin[off] = h;
        h = fmaf(p, h, s);
    }
}

// Phase C: replay with carry-in; y = (scan_y + u*D) * silu(z); write bf16 in-place over u.
__global__ __launch_bounds__(256) void scan_phaseC(
    const u16* __restrict__ delta,
    u16* __restrict__ u,              // in: u (bf16); out: yz (bf16, in-place)
    const float* __restrict__ xdbl,   // B at +64, C at +80
    const float* __restrict__ A_log,
    const float* __restrict__ Hin,
    const float* __restrict__ Dp,
    const u16* __restrict__ xzbf)     // silu(z) at col 2048+d, ld 4096 (pre-gated in GEMM)
{
    int d = blockIdx.x * 256 + threadIdx.x;
    int c = blockIdx.y, b = blockIdx.z;
    float Ad[NSTATE];
    #pragma unroll
    for (int n = 0; n < NSTATE; n++) Ad[n] = -__expf(A_log[(size_t)d * NSTATE + n]);
    float hs[NSTATE];
    size_t hbase = ((size_t)(b * NC + c) * DINNER + d) * NSTATE;
    #pragma unroll
    for (int n = 0; n < NSTATE; n++) hs[n] = Hin[hbase + n];
    float Dd = Dp[d];
    int r0 = b * SEQ + c * TS;
    for (int t = 0; t < TS; t++) {
        int r = r0 + t;
        float dlt = bf2f(delta[(size_t)r * DINNER + d]);
        float uu  = bf2f(u[(size_t)r * DINNER + d]);
        const float* bm = xdbl + (size_t)r * 96 + DTRANK;
        const float* cm = bm + NSTATE;
        float du = dlt * uu;
        float y = 0.f;
        #pragma unroll
        for (int n = 0; n < NSTATE; n++) {
            float dA = __expf(dlt * Ad[n]);
            hs[n] = fmaf(dA, hs[n], du * bm[n]);
            y = fmaf(hs[n], cm[n], y);
        }
        float sz = bf2f(xzbf[(size_t)r * 4096 + DINNER + d]);  // already silu'd
        u[(size_t)r * DINNER + d] = f2bf((y + uu * Dd) * sz);
    }
}

// ---------------- Final: out = x + rs * (y2 * w) ----------------
__global__ __launch_bounds__(256) void final_kernel(
    const float* __restrict__ x, const float* __restrict__ y2,
    const float* __restrict__ w, const float* __restrict__ rs,
    float* __restrict__ out)
{
    size_t i = ((size_t)blockIdx.x * 256 + threadIdx.x) * 4;
    float r = rs[0];
    float4 xv = *(const float4*)(x + i);
    float4 yv = *(const float4*)(y2 + i);
    float4 wv = *(const float4*)(w + i);
    float4 o;
    o.x = xv.x + r * yv.x * wv.x;
    o.y = xv.y + r * yv.y * wv.y;
    o.z = xv.z + r * yv.z * wv.z;
    o.w = xv.w + r * yv.w * wv.w;
    *(float4*)(out + i) = o;
}

extern "C" void kernel_launch(void* const* d_in, const int* in_sizes, int n_in,
                              void* d_out, int out_size, void* d_ws, size_t ws_size,
                              hipStream_t stream)
{
    const float* x         = (const float*)d_in[0];
    const float* ln_g      = (const float*)d_in[1];
    const float* ln_b      = (const float*)d_in[2];
    const float* sq_w      = (const float*)d_in[3];
    const float* sq_b      = (const float*)d_in[4];
    const float* srw_w     = (const float*)d_in[5];
    const float* srw_b     = (const float*)d_in[6];
    const float* res_scale = (const float*)d_in[7];
    const float* in_proj_w = (const float*)d_in[8];
    const float* conv_w    = (const float*)d_in[9];
    const float* conv_b    = (const float*)d_in[10];
    const float* x_proj_w  = (const float*)d_in[11];
    const float* dt_w      = (const float*)d_in[12];
    const float* dt_b      = (const float*)d_in[13];
    const float* A_log     = (const float*)d_in[14];
    const float* Dp        = (const float*)d_in[15];
    const float* out_proj_w= (const float*)d_in[16];
    float* out = (float*)d_out;

    // workspace layout (MB offsets), lifetime-based reuse:
    //  0-16 : h0 f32 (1-2) -> delta_bf 16MB (6-9) -> y2 f32 (10-12)
    // 16-32 : xpart 6MB (5)
    // 32-64 : xz_bf bf16 (3-9; u_raw cols 0..2047, silu(z) cols 2048..4095)
    // 64-80 : u_bf -> yz bf16 in place
    // 80-82 : xdbl f32 (1.5MB)
    // 82-83 : xprojT bf16 (0.5MB)
    // 83-91 : h0_bf (1-2) -> xdbl_bf (5-6)
    // 91-99 : h_bf (2-3) -> sumdlt 0.5MB (7-8)
    // 99-115: S f32 8.4MB (7-8) -> y2_bf (10-11)
    // 115-131: Hin f32 8.4MB (8-9) -> wbuf f32 (11-12)
    // 131-147.25: weight transposes (whole call)
    char* ws = (char*)d_ws;
    float* h0      = (float*)(ws + 0);
    u16*   delta_bf= (u16*)  (ws + 0);
    float* y2      = (float*)(ws + 0);
    float* xpart   = (float*)(ws + ((size_t)16 << 20));
    u16*   xz_bf   = (u16*)  (ws + ((size_t)32 << 20));
    u16*   u_bf    = (u16*)  (ws + ((size_t)64 << 20));
    float* xdbl    = (float*)(ws + ((size_t)80 << 20));
    u16*   xprojT  = (u16*)  (ws + ((size_t)82 << 20));
    u16*   h0_bf   = (u16*)  (ws + ((size_t)83 << 20));
    u16*   xdbl_bf = (u16*)  (ws + ((size_t)83 << 20));
    u16*   h_bf    = (u16*)  (ws + ((size_t)91 << 20));
    float* sumdlt  = (float*)(ws + ((size_t)91 << 20));
    float* S       = (float*)(ws + ((size_t)99 << 20));
    u16*   y2_bf   = (u16*)  (ws + ((size_t)99 << 20));
    float* Hin     = (float*)(ws + ((size_t)115 << 20));
    float* wbuf    = (float*)(ws + ((size_t)115 << 20));
    u16*   sqT     = (u16*)  (ws + ((size_t)131 << 20));
    u16*   srwT    = (u16*)  (ws + ((size_t)133 << 20));
    u16*   inprojT = (u16*)  (ws + ((size_t)135 << 20));
    u16*   outprojT= (u16*)  (ws + ((size_t)143 << 20));
    u16*   dtT     = (u16*)  (ws + ((size_t)147 << 20));

    dim3 blk(256), tblk(32, 8);

    // 0) weight transpose-convert to bf16 [N,K]
    transpose_bf16<<<dim3(32, 32),  tblk, 0, stream>>>(sq_w,      sqT,      DMODEL, DMODEL);
    transpose_bf16<<<dim3(32, 32),  tblk, 0, stream>>>(srw_w,     srwT,     DMODEL, DMODEL);
    transpose_bf16<<<dim3(128, 32), tblk, 0, stream>>>(in_proj_w, inprojT,  DMODEL, 2 * DINNER);
    transpose_bf16<<<dim3(32, 64),  tblk, 0, stream>>>(out_proj_w,outprojT, DINNER, DMODEL);
    transpose_bf16<<<dim3(4, 64),   tblk, 0, stream>>>(x_proj_w,  xprojT,   DINNER, 96);   // pad 96->128 rows
    transpose_bf16<<<dim3(64, 2),   tblk, 0, stream>>>(dt_w,      dtT,      DTRANK, DINNER);

    // 1) LayerNorm -> h0 f32 + h0_bf
    ln_kernel<<<ROWS, blk, 0, stream>>>(x, ln_g, ln_b, h0, h0_bf);
    // 2) h_bf = bf16(h0 + h0@sq_w + sq_b)
    gemm_bf16<0, true, true, true, false><<<dim3(8, 32), blk, 0, stream>>>(
        h0_bf, sqT, nullptr, h_bf, sq_b, h0, DMODEL, DMODEL, DMODEL, DMODEL, DMODEL, 0);
    // 3) xz_bf = bf16(h @ in_proj_w), silu fused onto z-half  — 256^2 2-phase kernel
    gemm256_bf16<true><<<dim3(16, 16), dim3(512), 0, stream>>>(
        h_bf, inprojT, xz_bf, DMODEL, DMODEL, DMODEL, 2 * DINNER);
    // 4) u_bf = bf16(silu(causal_dwconv(xz_bf[:, :2048])))
    conv_silu_kernel<<<(ROWS * DINNER) / 256, blk, 0, stream>>>(xz_bf, conv_w, conv_b, u_bf);
    // 5) x_proj split-K=4: partials -> xpart, then reduce
    gemm_bf16<0, false, false, false, true><<<dim3(1, 32, 4), blk, 0, stream>>>(
        u_bf, xprojT, xpart, nullptr, nullptr, nullptr, DINNER, DINNER, DINNER, 96, 96, DINNER / 4);
    reduce_xproj<<<(ROWS * 96) / 256, blk, 0, stream>>>(xpart, xdbl, xdbl_bf);
    // 6) delta_bf = bf16(softplus(xdbl[:, :64] @ dt_w + dt_b))
    gemm_bf16<1, true, false, true, false><<<dim3(16, 32), blk, 0, stream>>>(
        xdbl_bf, dtT, nullptr, delta_bf, dt_b, nullptr, DTRANK, 96, DTRANK, DINNER, DINNER, 0);
    // 7-9) chunked scan (fp32 state)
    scan_phaseA<<<dim3(DINNER / 256, NC, BATCH), blk, 0, stream>>>(delta_bf, u_bf, xdbl, A_log, S, sumdlt);
    scan_phaseB<<<dim3((BATCH * DINNER * NSTATE) / 256), blk, 0, stream>>>(S, sumdlt, A_log, Hin);
    scan_phaseC<<<dim3(DINNER / 256, NC, BATCH), blk, 0, stream>>>(delta_bf, u_bf, xdbl, A_log, Hin, Dp, xz_bf);
    // 10) y2 = yz @ out_proj_w  (f32 + bf16)
    gemm_bf16<0, false, false, true, true><<<dim3(8, 32), blk, 0, stream>>>(
        u_bf, outprojT, y2, y2_bf, nullptr, nullptr, DINNER, DINNER, DINNER, DMODEL, DMODEL, 0);
    // 11) wbuf = y2 @ srw_w + srw_b
    gemm_bf16<0, true, false, false, true><<<dim3(8, 32), blk, 0, stream>>>(
        y2_bf, srwT, wbuf, nullptr, srw_b, nullptr, DMODEL, DMODEL, DMODEL, DMODEL, DMODEL, 0);
    // 12) out = x + res_scale * (y2 * wbuf)
    final_kernel<<<(ROWS * DMODEL) / (256 * 4), blk, 0, stream>>>(x, y2, wbuf, res_scale, out);
}

// Round 5
// 315.786 us; speedup vs baseline: 4.9930x; 1.0672x over previous
//
#include <hip/hip_runtime.h>
#include <math.h>

// Topoformer-Mamba block. Round 5: depth-2 counted-vmcnt in_proj, srw+final fusion,
// merged transposes, split-K=8 x_proj.
// B=2, L=2048, D_MODEL=1024, D_INNER=2048, N(state)=16, DT_RANK=64, d_conv=4.

#define DMODEL 1024
#define DINNER 2048
#define NSTATE 16
#define DTRANK 64
#define BATCH  2
#define SEQ    2048
#define ROWS   (BATCH*SEQ)     // 4096
#define NC     32              // scan chunks
#define TS     (SEQ/NC)        // 64 steps per chunk
#define LN_EPS 1e-5f

typedef unsigned short u16;
typedef __attribute__((ext_vector_type(8))) short bf16x8;
typedef __attribute__((ext_vector_type(4))) float f32x4;

__device__ __forceinline__ float silu_f(float x) { return x / (1.f + __expf(-x)); }

__device__ __forceinline__ u16 f2bf(float f) {
    union { float f; unsigned u; } v; v.f = f;
    unsigned r = v.u + 0x7fffu + ((v.u >> 16) & 1u);
    return (u16)(r >> 16);
}
__device__ __forceinline__ float bf2f(u16 h) {
    union { unsigned u; float f; } v; v.u = ((unsigned)h) << 16; return v.f;
}

__device__ __forceinline__ void gload_lds16(const u16* g, u16* l) {
    __builtin_amdgcn_global_load_lds(
        (const __attribute__((address_space(1))) unsigned int*)(g),
        (__attribute__((address_space(3))) unsigned int*)(static_cast<void*>(l)),
        16, 0, 0);
}

// ---------------- LayerNorm (one block per row), writes f32 + bf16 ----------------
__global__ __launch_bounds__(256) void ln_kernel(const float* __restrict__ x,
                                                 const float* __restrict__ g,
                                                 const float* __restrict__ bta,
                                                 float* __restrict__ out,
                                                 u16* __restrict__ outbf)
{
    int row = blockIdx.x;
    const float* xr = x + (size_t)row * DMODEL;
    float4 v = ((const float4*)xr)[threadIdx.x];
    float s  = v.x + v.y + v.z + v.w;
    float ss = v.x*v.x + v.y*v.y + v.z*v.z + v.w*v.w;
    #pragma unroll
    for (int off = 32; off; off >>= 1) { s += __shfl_down(s, off); ss += __shfl_down(ss, off); }
    __shared__ float s_s[4], s_ss[4];
    int lane = threadIdx.x & 63, w = threadIdx.x >> 6;
    if (lane == 0) { s_s[w] = s; s_ss[w] = ss; }
    __syncthreads();
    float ts = 0.f, tss = 0.f;
    #pragma unroll
    for (int i = 0; i < 4; i++) { ts += s_s[i]; tss += s_ss[i]; }
    float mu  = ts / (float)DMODEL;
    float var = tss / (float)DMODEL - mu * mu;
    float rstd = rsqrtf(var + LN_EPS);
    float4 gv = ((const float4*)g)[threadIdx.x];
    float4 bv = ((const float4*)bta)[threadIdx.x];
    float4 o;
    o.x = (v.x - mu) * rstd * gv.x + bv.x;
    o.y = (v.y - mu) * rstd * gv.y + bv.y;
    o.z = (v.z - mu) * rstd * gv.z + bv.z;
    o.w = (v.w - mu) * rstd * gv.w + bv.w;
    ((float4*)(out + (size_t)row * DMODEL))[threadIdx.x] = o;
    unsigned lo = (unsigned)f2bf(o.x) | ((unsigned)f2bf(o.y) << 16);
    unsigned hi = (unsigned)f2bf(o.z) | ((unsigned)f2bf(o.w) << 16);
    ((uint2*)(outbf + (size_t)row * DMODEL))[threadIdx.x] = make_uint2(lo, hi);
}

// ---------------- All weight transposes in ONE dispatch ----------------
// dst[c][r] = bf16(src[r][c]); dst rows beyond C zero-filled (xproj pad 96->128).
__device__ __forceinline__ void tr_tile(const float* __restrict__ src,
                                        u16* __restrict__ dst,
                                        int R, int C, int xt, int yt)
{
    __shared__ float t[32][33];
    int c0 = xt * 32, r0 = yt * 32;
    int x = threadIdx.x, y = threadIdx.y;
    #pragma unroll
    for (int i = 0; i < 32; i += 8) {
        float v = 0.f;
        if (c0 + x < C) v = src[(size_t)(r0 + y + i) * C + c0 + x];
        t[y + i][x] = v;
    }
    __syncthreads();
    #pragma unroll
    for (int i = 0; i < 32; i += 8)
        dst[(size_t)(c0 + y + i) * R + r0 + x] = f2bf(t[x][y + i]);
}

__global__ __launch_bounds__(256) void transpose_all(
    const float* __restrict__ sq_w,  u16* __restrict__ sqT,
    const float* __restrict__ srw_w, u16* __restrict__ srwT,
    const float* __restrict__ inp,   u16* __restrict__ inpT,
    const float* __restrict__ outp,  u16* __restrict__ outpT,
    const float* __restrict__ xp,    u16* __restrict__ xpT,
    const float* __restrict__ dtw,   u16* __restrict__ dtT)
{
    int id = blockIdx.x;
    if (id < 1024)      { tr_tile(sq_w,  sqT,  1024, 1024, id & 31,  id >> 5); }
    else if (id < 2048) { id -= 1024; tr_tile(srw_w, srwT, 1024, 1024, id & 31,  id >> 5); }
    else if (id < 6144) { id -= 2048; tr_tile(inp,  inpT, 1024, 4096, id & 127, id >> 7); }
    else if (id < 8192) { id -= 6144; tr_tile(outp, outpT,2048, 1024, id & 31,  id >> 5); }
    else if (id < 8448) { id -= 8192; tr_tile(xp,   xpT,  2048,   96, id & 3,   id >> 2); } // pad->128
    else                { id -= 8448; tr_tile(dtw,  dtT,    64, 2048, id & 63,  id >> 6); }
}

// ---------------- 128^2 bf16 MFMA GEMM (m97 structure) ----------------
// ACT: 0=none, 1=softplus. splitK>0: blockIdx.z selects K-slice, C partial slabs.
// FUSE_FINAL: writes C[row,col] = xres + rs * res(y2) * (acc+bias)  (srw+final fusion)
template<int ACT, bool HAS_BIAS, bool HAS_RES, bool WRITE_BF16, bool WRITE_F32, bool FUSE_FINAL>
__global__ __launch_bounds__(256) void gemm_bf16(
    const u16* __restrict__ A, const u16* __restrict__ Bt,
    float* __restrict__ C, u16* __restrict__ Cbf,
    const float* __restrict__ bias, const float* __restrict__ res,
    const float* __restrict__ xres, const float* __restrict__ rsp,
    int K, int lda, int ldb, int ldc, int Nout, int splitK)
{
    if (splitK) {
        int sp = blockIdx.z;
        A  += (size_t)sp * splitK;
        Bt += (size_t)sp * splitK;
        C  += (size_t)sp * ROWS * ldc;
        K = splitK;
    }
    __shared__ __align__(16) u16 As[128 * 32];
    __shared__ __align__(16) u16 Bs[128 * 32];
    const int tid = threadIdx.x;
    const int wv = tid >> 6, ln = tid & 63;
    const int m0 = blockIdx.y * 128, n0 = blockIdx.x * 128;
    const int g = ln >> 4, r = ln & 15;
    const int wr = wv >> 1, wc = wv & 1;

    const u16* a_g0 = A + (size_t)(m0 + (tid >> 2)) * lda + (tid & 3) * 8;
    const u16* a_g1 = a_g0 + (size_t)64 * lda;
    const u16* b_g0 = Bt + (size_t)(n0 + (tid >> 2)) * ldb + (tid & 3) * 8;
    const u16* b_g1 = b_g0 + (size_t)64 * ldb;
    u16* a_l = As + wv * 512;
    u16* b_l = Bs + wv * 512;

    f32x4 acc[4][4];
    #pragma unroll
    for (int i = 0; i < 4; i++)
        #pragma unroll
        for (int j = 0; j < 4; j++) acc[i][j] = (f32x4)0.f;

    for (int k0 = 0; k0 < K; k0 += 32) {
        __syncthreads();
        gload_lds16(a_g0 + k0, a_l);
        gload_lds16(a_g1 + k0, a_l + 2048);
        gload_lds16(b_g0 + k0, b_l);
        gload_lds16(b_g1 + k0, b_l + 2048);
        __syncthreads();
        bf16x8 av[4], bv[4];
        #pragma unroll
        for (int mi = 0; mi < 4; mi++)
            av[mi] = *(const bf16x8*)&As[(wr * 64 + mi * 16 + r) * 32 + g * 8];
        #pragma unroll
        for (int ni = 0; ni < 4; ni++)
            bv[ni] = *(const bf16x8*)&Bs[(wc * 64 + ni * 16 + r) * 32 + g * 8];
        #pragma unroll
        for (int mi = 0; mi < 4; mi++)
            #pragma unroll
            for (int ni = 0; ni < 4; ni++)
                acc[mi][ni] = __builtin_amdgcn_mfma_f32_16x16x32_bf16(av[mi], bv[ni], acc[mi][ni], 0, 0, 0);
    }

    // C/D layout (verified m89/m91): col = lane&15, row = (lane>>4)*4 + reg
    float rs = FUSE_FINAL ? rsp[0] : 0.f;
    #pragma unroll
    for (int mi = 0; mi < 4; mi++) {
        int row0 = m0 + wr * 64 + mi * 16 + g * 4;
        #pragma unroll
        for (int ni = 0; ni < 4; ni++) {
            int col = n0 + wc * 64 + ni * 16 + r;
            if (col >= Nout) continue;
            float bb = HAS_BIAS ? bias[col] : 0.f;
            #pragma unroll
            for (int j = 0; j < 4; j++) {
                int row = row0 + j;
                float c = acc[mi][ni][j] + bb;
                if (HAS_RES) c += res[(size_t)row * ldc + col];
                if (ACT == 1) c = logf(1.f + __expf(c));       // softplus
                if (FUSE_FINAL) {
                    float yv = res[(size_t)row * ldc + col];   // y2 f32
                    c = xres[(size_t)row * ldc + col] + rs * yv * c;
                }
                if (WRITE_F32 || FUSE_FINAL) C[(size_t)row * ldc + col] = c;
                if (WRITE_BF16) Cbf[(size_t)row * ldc + col] = f2bf(c);
            }
        }
    }
}

// ---------------- 256^2 depth-2 counted-vmcnt bf16 GEMM (in_proj) ----------------
// BM=BN=256, BK=32, 512 thr = 8 waves (2M x 4N), per-wave 128x64 = 8x4 MFMA frags.
// LDS 96 KB: 3 bufs x (A 16KB + B 16KB). Stage t+2 each iter; drain vmcnt(4)
// (stage t+1 done, t+2's 4 loads stay in flight) — never vmcnt(0) mid-loop.
// XOR seg-swizzle both sides (rule #21). Epilogue: bf16 out; silu on cols>=DINNER.
__device__ __forceinline__ void stage256(const u16* __restrict__ A, const u16* __restrict__ Bt,
                                         int m0, int n0, int lda, int ldb, int k0,
                                         u16* As, u16* Bs, int tid)
{
    #pragma unroll
    for (int p = 0; p < 2; p++) {
        int idx = p * 512 + tid;
        int row = idx >> 2, seg = idx & 3;
        int sseg = seg ^ ((row >> 1) & 3);
        gload_lds16(A  + (size_t)(m0 + row) * lda + k0 + sseg * 8, As + idx * 8);
        gload_lds16(Bt + (size_t)(n0 + row) * ldb + k0 + sseg * 8, Bs + idx * 8);
    }
}

template<bool ZSILU>
__global__ __launch_bounds__(512, 1) void gemm256_bf16(
    const u16* __restrict__ A, const u16* __restrict__ Bt, u16* __restrict__ Cbf,
    int K, int lda, int ldb, int ldc)
{
    __shared__ __align__(16) u16 As[3][8192];
    __shared__ __align__(16) u16 Bs[3][8192];
    const int tid = threadIdx.x;
    const int wv = tid >> 6, ln = tid & 63;
    const int g = ln >> 4, r = ln & 15;
    const int wr = wv >> 2, wc = wv & 3;
    const int m0 = blockIdx.y * 256, n0 = blockIdx.x * 256;

    f32x4 acc[8][4];
    #pragma unroll
    for (int i = 0; i < 8; i++)
        #pragma unroll
        for (int j = 0; j < 4; j++) acc[i][j] = (f32x4)0.f;

    const int nt = K >> 5;   // K=1024 -> 32 tiles (nt >= 3 assumed)
    stage256(A, Bt, m0, n0, lda, ldb, 0,  As[0], Bs[0], tid);   // 4 loads
    stage256(A, Bt, m0, n0, lda, ldb, 32, As[1], Bs[1], tid);   // 4 loads
    asm volatile("s_waitcnt vmcnt(4)" ::: "memory");            // stage0 done
    __builtin_amdgcn_s_barrier();
    __builtin_amdgcn_sched_barrier(0);

    for (int t = 0; t < nt; ++t) {
        const int cur = t % 3;
        if (t + 2 < nt)
            stage256(A, Bt, m0, n0, lda, ldb, (t + 2) << 5,
                     As[(t + 2) % 3], Bs[(t + 2) % 3], tid);
        bf16x8 av[8], bv[4];
        #pragma unroll
        for (int mi = 0; mi < 8; mi++) {
            int arow = wr * 128 + mi * 16 + r;
            av[mi] = *(const bf16x8*)&As[cur][arow * 32 + ((g ^ ((arow >> 1) & 3)) << 3)];
        }
        #pragma unroll
        for (int ni = 0; ni < 4; ni++) {
            int brow = wc * 64 + ni * 16 + r;
            bv[ni] = *(const bf16x8*)&Bs[cur][brow * 32 + ((g ^ ((brow >> 1) & 3)) << 3)];
        }
        #pragma unroll
        for (int mi = 0; mi < 8; mi++)
            #pragma unroll
            for (int ni = 0; ni < 4; ni++)
                acc[mi][ni] = __builtin_amdgcn_mfma_f32_16x16x32_bf16(av[mi], bv[ni], acc[mi][ni], 0, 0, 0);
        if (t + 1 < nt) {
            if (t + 2 < nt) asm volatile("s_waitcnt vmcnt(4)" ::: "memory"); // stage(t+1) done
            else            asm volatile("s_waitcnt vmcnt(0)" ::: "memory"); // tail: nothing deeper
            __builtin_amdgcn_s_barrier();
            __builtin_amdgcn_sched_barrier(0);
        }
    }

    const bool isz = ZSILU && (n0 >= DINNER);
    #pragma unroll
    for (int mi = 0; mi < 8; mi++) {
        int row0 = m0 + wr * 128 + mi * 16 + g * 4;
        #pragma unroll
        for (int ni = 0; ni < 4; ni++) {
            int col = n0 + wc * 64 + ni * 16 + r;
            #pragma unroll
            for (int j = 0; j < 4; j++) {
                float c = acc[mi][ni][j];
                if (isz) c = silu_f(c);
                Cbf[(size_t)(row0 + j) * ldc + col] = f2bf(c);
            }
        }
    }
}

// ---------------- Reduce split-K partials for x_proj (8 slabs) ----------------
__global__ __launch_bounds__(256) void reduce_xproj(const float* __restrict__ part,
                                                    float* __restrict__ xdbl,
                                                    u16* __restrict__ xdbl_bf)
{
    int i = blockIdx.x * 256 + threadIdx.x;  // ROWS*96
    const int SL = ROWS * 96;
    float s = 0.f;
    #pragma unroll
    for (int k = 0; k < 8; k++) s += part[i + k * SL];
    xdbl[i] = s;
    xdbl_bf[i] = f2bf(s);
}

// ---------------- Causal depthwise conv (d_conv=4) + SiLU -> bf16 u ----------------
__global__ __launch_bounds__(256) void conv_silu_kernel(
    const u16* __restrict__ xzbf, const float* __restrict__ w,
    const float* __restrict__ b, u16* __restrict__ u)
{
    size_t idx = (size_t)blockIdx.x * 256 + threadIdx.x;  // ROWS*DINNER
    int d = (int)(idx & (DINNER - 1));
    int r = (int)(idx >> 11);
    int t = r & (SEQ - 1);
    float4 wv = *(const float4*)(w + (size_t)d * 4);
    float acc = b[d];
    const float* wf = (const float*)&wv;
    #pragma unroll
    for (int j = 0; j < 4; j++) {
        int tt = t - 3 + j;
        if (tt >= 0)
            acc = fmaf(bf2f(xzbf[(size_t)(r - 3 + j) * 4096 + d]), wf[j], acc);
    }
    u[idx] = f2bf(silu_f(acc));
}

// ---------------- Chunked selective scan (fp32 state; bf16 delta/u/z) ----------------
__global__ __launch_bounds__(256) void scan_phaseA(
    const u16* __restrict__ delta,
    const u16* __restrict__ u,
    const float* __restrict__ xdbl,   // [ROWS,96]; B at +64
    const float* __restrict__ A_log,
    float* __restrict__ S, float* __restrict__ sumdlt)
{
    int d = blockIdx.x * 256 + threadIdx.x;
    int c = blockIdx.y, b = blockIdx.z;
    float Ad[NSTATE];
    #pragma unroll
    for (int n = 0; n < NSTATE; n++) Ad[n] = -__expf(A_log[(size_t)d * NSTATE + n]);
    float hs[NSTATE];
    #pragma unroll
    for (int n = 0; n < NSTATE; n++) hs[n] = 0.f;
    float sd = 0.f;
    int r0 = b * SEQ + c * TS;
    for (int t = 0; t < TS; t++) {
        int r = r0 + t;
        float dlt = bf2f(delta[(size_t)r * DINNER + d]);
        float uu  = bf2f(u[(size_t)r * DINNER + d]);
        const float* bm = xdbl + (size_t)r * 96 + DTRANK;
        float du = dlt * uu;
        sd += dlt;
        #pragma unroll
        for (int n = 0; n < NSTATE; n++) {
            float dA = __expf(dlt * Ad[n]);
            hs[n] = fmaf(dA, hs[n], du * bm[n]);
        }
    }
    size_t base = ((size_t)(b * NC + c) * DINNER + d) * NSTATE;
    #pragma unroll
    for (int n = 0; n < NSTATE; n += 4)
        *(float4*)(S + base + n) = make_float4(hs[n], hs[n+1], hs[n+2], hs[n+3]);
    sumdlt[(size_t)(b * NC + c) * DINNER + d] = sd;
}

__global__ __launch_bounds__(256) void scan_phaseB(
    const float* __restrict__ S, const float* __restrict__ sumdlt,
    const float* __restrict__ A_log, float* __restrict__ Hin)
{
    int idx = blockIdx.x * 256 + threadIdx.x;   // BATCH*DINNER*NSTATE
    int b  = idx >> 15;
    int dn = idx & (DINNER * NSTATE - 1);
    float Ad = -__expf(A_log[dn]);
    int d = dn >> 4;
    const size_t stride = (size_t)DINNER * NSTATE;
    size_t base  = (size_t)b * NC * stride + dn;
    size_t sbase = (size_t)b * NC * DINNER + d;
    float h = 0.f;
    for (int c = 0; c < NC; c++) {
        size_t off = base + (size_t)c * stride;
        float p = __expf(Ad * sumdlt[sbase + (size_t)c * DINNER]);
        float s = S[off];
        Hin[off] = h;
        h = fmaf(p, h, s);
    }
}

__global__ __launch_bounds__(256) void scan_phaseC(
    const u16* __restrict__ delta,
    u16* __restrict__ u,              // in: u (bf16); out: yz (bf16, in-place)
    const float* __restrict__ xdbl,   // B at +64, C at +80
    const float* __restrict__ A_log,
    const float* __restrict__ Hin,
    const float* __restrict__ Dp,
    const u16* __restrict__ xzbf)     // silu(z) at col 2048+d, ld 4096 (pre-gated)
{
    int d = blockIdx.x * 256 + threadIdx.x;
    int c = blockIdx.y, b = blockIdx.z;
    float Ad[NSTATE];
    #pragma unroll
    for (int n = 0; n < NSTATE; n++) Ad[n] = -__expf(A_log[(size_t)d * NSTATE + n]);
    float hs[NSTATE];
    size_t hbase = ((size_t)(b * NC + c) * DINNER + d) * NSTATE;
    #pragma unroll
    for (int n = 0; n < NSTATE; n++) hs[n] = Hin[hbase + n];
    float Dd = Dp[d];
    int r0 = b * SEQ + c * TS;
    for (int t = 0; t < TS; t++) {
        int r = r0 + t;
        float dlt = bf2f(delta[(size_t)r * DINNER + d]);
        float uu  = bf2f(u[(size_t)r * DINNER + d]);
        const float* bm = xdbl + (size_t)r * 96 + DTRANK;
        const float* cm = bm + NSTATE;
        float du = dlt * uu;
        float y = 0.f;
        #pragma unroll
        for (int n = 0; n < NSTATE; n++) {
            float dA = __expf(dlt * Ad[n]);
            hs[n] = fmaf(dA, hs[n], du * bm[n]);
            y = fmaf(hs[n], cm[n], y);
        }
        float sz = bf2f(xzbf[(size_t)r * 4096 + DINNER + d]);
        u[(size_t)r * DINNER + d] = f2bf((y + uu * Dd) * sz);
    }
}

extern "C" void kernel_launch(void* const* d_in, const int* in_sizes, int n_in,
                              void* d_out, int out_size, void* d_ws, size_t ws_size,
                              hipStream_t stream)
{
    const float* x         = (const float*)d_in[0];
    const float* ln_g      = (const float*)d_in[1];
    const float* ln_b      = (const float*)d_in[2];
    const float* sq_w      = (const float*)d_in[3];
    const float* sq_b      = (const float*)d_in[4];
    const float* srw_w     = (const float*)d_in[5];
    const float* srw_b     = (const float*)d_in[6];
    const float* res_scale = (const float*)d_in[7];
    const float* in_proj_w = (const float*)d_in[8];
    const float* conv_w    = (const float*)d_in[9];
    const float* conv_b    = (const float*)d_in[10];
    const float* x_proj_w  = (const float*)d_in[11];
    const float* dt_w      = (const float*)d_in[12];
    const float* dt_b      = (const float*)d_in[13];
    const float* A_log     = (const float*)d_in[14];
    const float* Dp        = (const float*)d_in[15];
    const float* out_proj_w= (const float*)d_in[16];
    float* out = (float*)d_out;

    // workspace layout (MB offsets), lifetime-based reuse:
    //  0-16 : h0 f32 (1-2) -> delta_bf 16MB (6-9) -> y2 f32 (10-11)
    // 16-32 : xpart 12MB (5)
    // 32-64 : xz_bf bf16 (3-9)
    // 64-80 : u_bf -> yz bf16 in place
    // 80-82 : xdbl f32 (1.5MB)
    // 82-83 : xprojT bf16 (0.5MB)
    // 83-91 : h0_bf (1-2) -> xdbl_bf (5-6)
    // 91-99 : h_bf (2-3) -> sumdlt 0.5MB (7-8)
    // 99-115: S f32 8.4MB (7-8) -> y2_bf (10-11)
    // 115-131: Hin f32 8.4MB (8-9)
    // 131-147.25: weight transposes (whole call)
    char* ws = (char*)d_ws;
    float* h0      = (float*)(ws + 0);
    u16*   delta_bf= (u16*)  (ws + 0);
    float* y2      = (float*)(ws + 0);
    float* xpart   = (float*)(ws + ((size_t)16 << 20));
    u16*   xz_bf   = (u16*)  (ws + ((size_t)32 << 20));
    u16*   u_bf    = (u16*)  (ws + ((size_t)64 << 20));
    float* xdbl    = (float*)(ws + ((size_t)80 << 20));
    u16*   xprojT  = (u16*)  (ws + ((size_t)82 << 20));
    u16*   h0_bf   = (u16*)  (ws + ((size_t)83 << 20));
    u16*   xdbl_bf = (u16*)  (ws + ((size_t)83 << 20));
    u16*   h_bf    = (u16*)  (ws + ((size_t)91 << 20));
    float* sumdlt  = (float*)(ws + ((size_t)91 << 20));
    float* S       = (float*)(ws + ((size_t)99 << 20));
    u16*   y2_bf   = (u16*)  (ws + ((size_t)99 << 20));
    float* Hin     = (float*)(ws + ((size_t)115 << 20));
    u16*   sqT     = (u16*)  (ws + ((size_t)131 << 20));
    u16*   srwT    = (u16*)  (ws + ((size_t)133 << 20));
    u16*   inprojT = (u16*)  (ws + ((size_t)135 << 20));
    u16*   outprojT= (u16*)  (ws + ((size_t)143 << 20));
    u16*   dtT     = (u16*)  (ws + ((size_t)147 << 20));

    dim3 blk(256), tblk(32, 8);

    // 0) all weight transposes, one dispatch (8576 tiles)
    transpose_all<<<8576, tblk, 0, stream>>>(sq_w, sqT, srw_w, srwT, in_proj_w, inprojT,
                                             out_proj_w, outprojT, x_proj_w, xprojT, dt_w, dtT);
    // 1) LayerNorm -> h0 f32 + h0_bf
    ln_kernel<<<ROWS, blk, 0, stream>>>(x, ln_g, ln_b, h0, h0_bf);
    // 2) h_bf = bf16(h0 + h0@sq_w + sq_b)
    gemm_bf16<0, true, true, true, false, false><<<dim3(8, 32), blk, 0, stream>>>(
        h0_bf, sqT, nullptr, h_bf, sq_b, h0, nullptr, nullptr, DMODEL, DMODEL, DMODEL, DMODEL, DMODEL, 0);
    // 3) xz_bf = bf16(h @ in_proj_w), silu fused onto z-half — depth-2 256^2 kernel
    gemm256_bf16<true><<<dim3(16, 16), dim3(512), 0, stream>>>(
        h_bf, inprojT, xz_bf, DMODEL, DMODEL, DMODEL, 2 * DINNER);
    // 4) u_bf = bf16(silu(causal_dwconv(xz_bf[:, :2048])))
    conv_silu_kernel<<<(ROWS * DINNER) / 256, blk, 0, stream>>>(xz_bf, conv_w, conv_b, u_bf);
    // 5) x_proj split-K=8: partials -> xpart, then reduce
    gemm_bf16<0, false, false, false, true, false><<<dim3(1, 32, 8), blk, 0, stream>>>(
        u_bf, xprojT, xpart, nullptr, nullptr, nullptr, nullptr, nullptr,
        DINNER, DINNER, DINNER, 96, 96, DINNER / 8);
    reduce_xproj<<<(ROWS * 96) / 256, blk, 0, stream>>>(xpart, xdbl, xdbl_bf);
    // 6) delta_bf = bf16(softplus(xdbl[:, :64] @ dt_w + dt_b))
    gemm_bf16<1, true, false, true, false, false><<<dim3(16, 32), blk, 0, stream>>>(
        xdbl_bf, dtT, nullptr, delta_bf, dt_b, nullptr, nullptr, nullptr,
        DTRANK, 96, DTRANK, DINNER, DINNER, 0);
    // 7-9) chunked scan (fp32 state)
    scan_phaseA<<<dim3(DINNER / 256, NC, BATCH), blk, 0, stream>>>(delta_bf, u_bf, xdbl, A_log, S, sumdlt);
    scan_phaseB<<<dim3((BATCH * DINNER * NSTATE) / 256), blk, 0, stream>>>(S, sumdlt, A_log, Hin);
    scan_phaseC<<<dim3(DINNER / 256, NC, BATCH), blk, 0, stream>>>(delta_bf, u_bf, xdbl, A_log, Hin, Dp, xz_bf);
    // 10) y2 = yz @ out_proj_w  (f32 + bf16)
    gemm_bf16<0, false, false, true, true, false><<<dim3(8, 32), blk, 0, stream>>>(
        u_bf, outprojT, y2, y2_bf, nullptr, nullptr, nullptr, nullptr,
        DINNER, DINNER, DINNER, DMODEL, DMODEL, 0);
    // 11+12) out = x + rs * (y2 * (y2@srw_w + srw_b))  — fused epilogue
    gemm_bf16<0, true, false, false, false, true><<<dim3(8, 32), blk, 0, stream>>>(
        y2_bf, srwT, out, nullptr, srw_b, y2, x, res_scale,
        DMODEL, DMODEL, DMODEL, DMODEL, DMODEL, 0);
}

// Round 6
// 279.040 us; speedup vs baseline: 5.6506x; 1.1317x over previous
//
#include <hip/hip_runtime.h>
#include <math.h>

// Topoformer-Mamba block. Round 6: register ds_read pipelining (LDS∥MFMA overlap)
// in both GEMM kernels, XOR swizzle on 128^2, merged prologue.
// B=2, L=2048, D_MODEL=1024, D_INNER=2048, N(state)=16, DT_RANK=64, d_conv=4.

#define DMODEL 1024
#define DINNER 2048
#define NSTATE 16
#define DTRANK 64
#define BATCH  2
#define SEQ    2048
#define ROWS   (BATCH*SEQ)     // 4096
#define NC     32              // scan chunks
#define TS     (SEQ/NC)        // 64 steps per chunk
#define LN_EPS 1e-5f

typedef unsigned short u16;
typedef __attribute__((ext_vector_type(8))) short bf16x8;
typedef __attribute__((ext_vector_type(4))) float f32x4;

__device__ __forceinline__ float silu_f(float x) { return x / (1.f + __expf(-x)); }

__device__ __forceinline__ u16 f2bf(float f) {
    union { float f; unsigned u; } v; v.f = f;
    unsigned r = v.u + 0x7fffu + ((v.u >> 16) & 1u);
    return (u16)(r >> 16);
}
__device__ __forceinline__ float bf2f(u16 h) {
    union { unsigned u; float f; } v; v.u = ((unsigned)h) << 16; return v.f;
}

__device__ __forceinline__ void gload_lds16(const u16* g, u16* l) {
    __builtin_amdgcn_global_load_lds(
        (const __attribute__((address_space(1))) unsigned int*)(g),
        (__attribute__((address_space(3))) unsigned int*)(static_cast<void*>(l)),
        16, 0, 0);
}

// ---------------- Merged prologue: all weight transposes + LayerNorm ----------------
__device__ __forceinline__ void tr_tile(const float* __restrict__ src,
                                        u16* __restrict__ dst,
                                        int R, int C, int xt, int yt, int tx, int ty)
{
    __shared__ float t[32][33];
    int c0 = xt * 32, r0 = yt * 32;
    #pragma unroll
    for (int i = 0; i < 32; i += 8) {
        float v = 0.f;
        if (c0 + tx < C) v = src[(size_t)(r0 + ty + i) * C + c0 + tx];
        t[ty + i][tx] = v;
    }
    __syncthreads();
    #pragma unroll
    for (int i = 0; i < 32; i += 8)
        dst[(size_t)(c0 + ty + i) * R + r0 + tx] = f2bf(t[tx][ty + i]);
}

__global__ __launch_bounds__(256) void prologue_kernel(
    const float* __restrict__ sq_w,  u16* __restrict__ sqT,
    const float* __restrict__ srw_w, u16* __restrict__ srwT,
    const float* __restrict__ inp,   u16* __restrict__ inpT,
    const float* __restrict__ outp,  u16* __restrict__ outpT,
    const float* __restrict__ xp,    u16* __restrict__ xpT,
    const float* __restrict__ dtw,   u16* __restrict__ dtT,
    const float* __restrict__ x,     const float* __restrict__ ln_g,
    const float* __restrict__ ln_b,
    float* __restrict__ h0, u16* __restrict__ h0bf)
{
    int id = blockIdx.x;
    if (id < 8576) {
        int tx = threadIdx.x & 31, ty = threadIdx.x >> 5;
        if (id < 1024)      { tr_tile(sq_w,  sqT,  1024, 1024, id & 31,  id >> 5, tx, ty); }
        else if (id < 2048) { id -= 1024; tr_tile(srw_w, srwT, 1024, 1024, id & 31,  id >> 5, tx, ty); }
        else if (id < 6144) { id -= 2048; tr_tile(inp,  inpT, 1024, 4096, id & 127, id >> 7, tx, ty); }
        else if (id < 8192) { id -= 6144; tr_tile(outp, outpT,2048, 1024, id & 31,  id >> 5, tx, ty); }
        else if (id < 8448) { id -= 8192; tr_tile(xp,   xpT,  2048,   96, id & 3,   id >> 2, tx, ty); }
        else                { id -= 8448; tr_tile(dtw,  dtT,    64, 2048, id & 63,  id >> 6, tx, ty); }
        return;
    }
    // LayerNorm row
    int row = id - 8576;
    const float* xr = x + (size_t)row * DMODEL;
    float4 v = ((const float4*)xr)[threadIdx.x];
    float s  = v.x + v.y + v.z + v.w;
    float ss = v.x*v.x + v.y*v.y + v.z*v.z + v.w*v.w;
    #pragma unroll
    for (int off = 32; off; off >>= 1) { s += __shfl_down(s, off); ss += __shfl_down(ss, off); }
    __shared__ float s_s[4], s_ss[4];
    int lane = threadIdx.x & 63, w = threadIdx.x >> 6;
    if (lane == 0) { s_s[w] = s; s_ss[w] = ss; }
    __syncthreads();
    float ts = 0.f, tss = 0.f;
    #pragma unroll
    for (int i = 0; i < 4; i++) { ts += s_s[i]; tss += s_ss[i]; }
    float mu  = ts / (float)DMODEL;
    float var = tss / (float)DMODEL - mu * mu;
    float rstd = rsqrtf(var + LN_EPS);
    float4 gv = ((const float4*)ln_g)[threadIdx.x];
    float4 bv = ((const float4*)ln_b)[threadIdx.x];
    float4 o;
    o.x = (v.x - mu) * rstd * gv.x + bv.x;
    o.y = (v.y - mu) * rstd * gv.y + bv.y;
    o.z = (v.z - mu) * rstd * gv.z + bv.z;
    o.w = (v.w - mu) * rstd * gv.w + bv.w;
    ((float4*)(h0 + (size_t)row * DMODEL))[threadIdx.x] = o;
    unsigned lo = (unsigned)f2bf(o.x) | ((unsigned)f2bf(o.y) << 16);
    unsigned hi = (unsigned)f2bf(o.z) | ((unsigned)f2bf(o.w) << 16);
    ((uint2*)(h0bf + (size_t)row * DMODEL))[threadIdx.x] = make_uint2(lo, hi);
}

// ---------------- staging helpers (XOR seg-swizzle both sides, rule #21) ----------------
// 128-row tile: 256 threads x 2 loads; row = idx>>2, seg = idx&3, src seg ^= (row>>1)&3.
__device__ __forceinline__ void stage128(const u16* __restrict__ A, const u16* __restrict__ Bt,
                                         int m0, int n0, int lda, int ldb, int k0,
                                         u16* As, u16* Bs, int tid)
{
    #pragma unroll
    for (int p = 0; p < 2; p++) {
        int idx = p * 256 + tid;
        int row = idx >> 2, seg = idx & 3;
        int ss = seg ^ ((row >> 1) & 3);
        gload_lds16(A  + (size_t)(m0 + row) * lda + k0 + ss * 8, As + idx * 8);
        gload_lds16(Bt + (size_t)(n0 + row) * ldb + k0 + ss * 8, Bs + idx * 8);
    }
}
// 256-row tile: 512 threads x 2 loads.
__device__ __forceinline__ void stage256(const u16* __restrict__ A, const u16* __restrict__ Bt,
                                         int m0, int n0, int lda, int ldb, int k0,
                                         u16* As, u16* Bs, int tid)
{
    #pragma unroll
    for (int p = 0; p < 2; p++) {
        int idx = p * 512 + tid;
        int row = idx >> 2, seg = idx & 3;
        int ss = seg ^ ((row >> 1) & 3);
        gload_lds16(A  + (size_t)(m0 + row) * lda + k0 + ss * 8, As + idx * 8);
        gload_lds16(Bt + (size_t)(n0 + row) * ldb + k0 + ss * 8, Bs + idx * 8);
    }
}

// ---------------- pipelined phase bodies ----------------
// Ledger (per wave, per phase t):
//  [A] vmcnt(0) drains stage(t+1); barrier releases buf[(t+1)%3] + proves all waves
//      finished reading K-tile t-1 (their lgkm drained before MFMA(t-1)).
//  [B] 4 ds_read B(t) from buf[t%3]; sched_barrier pins issue order.
//  [C] prefetch A(t+1) into avW from buf[(t+1)%3] (in flight across MFMA).
//  [D] stage(t+2) -> buf[(t+2)%3] (old content t-1: reads globally done per [A]).
//  [E] lgkmcnt(#A-prefetch) drains A(t)+B(t), leaves A(t+1); MFMA on avR.
__device__ __forceinline__ void ph128(int t, int nt,
    const u16* __restrict__ A, const u16* __restrict__ Bt,
    int m0, int n0, int lda, int ldb, int tid, int wr, int wc, int g, int r,
    u16* As, u16* Bs, bf16x8 (&avR)[4], bf16x8 (&avW)[4], f32x4 (&acc)[4][4])
{
    if (t + 1 < nt) {
        asm volatile("s_waitcnt vmcnt(0)" ::: "memory");
        __builtin_amdgcn_s_barrier();
        __builtin_amdgcn_sched_barrier(0);
    }
    bf16x8 bv[4];
    {
        const u16* bc = Bs + (t % 3) * 4096;
        #pragma unroll
        for (int ni = 0; ni < 4; ni++) {
            int brow = wc * 64 + ni * 16 + r;
            bv[ni] = *(const bf16x8*)&bc[brow * 32 + ((g ^ ((brow >> 1) & 3)) << 3)];
        }
    }
    __builtin_amdgcn_sched_barrier(0);
    if (t + 1 < nt) {
        const u16* ac = As + ((t + 1) % 3) * 4096;
        #pragma unroll
        for (int mi = 0; mi < 4; mi++) {
            int arow = wr * 64 + mi * 16 + r;
            avW[mi] = *(const bf16x8*)&ac[arow * 32 + ((g ^ ((arow >> 1) & 3)) << 3)];
        }
    }
    if (t + 2 < nt)
        stage128(A, Bt, m0, n0, lda, ldb, (t + 2) << 5,
                 As + ((t + 2) % 3) * 4096, Bs + ((t + 2) % 3) * 4096, tid);
    if (t + 1 < nt) asm volatile("s_waitcnt lgkmcnt(4)" ::: "memory");
    else            asm volatile("s_waitcnt lgkmcnt(0)" ::: "memory");
    __builtin_amdgcn_sched_barrier(0);
    #pragma unroll
    for (int mi = 0; mi < 4; mi++)
        #pragma unroll
        for (int ni = 0; ni < 4; ni++)
            acc[mi][ni] = __builtin_amdgcn_mfma_f32_16x16x32_bf16(avR[mi], bv[ni], acc[mi][ni], 0, 0, 0);
}

__device__ __forceinline__ void ph256(int t, int nt,
    const u16* __restrict__ A, const u16* __restrict__ Bt,
    int m0, int n0, int lda, int ldb, int tid, int wr, int wc, int g, int r,
    u16* As, u16* Bs, bf16x8 (&avR)[8], bf16x8 (&avW)[8], f32x4 (&acc)[8][4])
{
    if (t + 1 < nt) {
        asm volatile("s_waitcnt vmcnt(0)" ::: "memory");
        __builtin_amdgcn_s_barrier();
        __builtin_amdgcn_sched_barrier(0);
    }
    bf16x8 bv[4];
    {
        const u16* bc = Bs + (t % 3) * 8192;
        #pragma unroll
        for (int ni = 0; ni < 4; ni++) {
            int brow = wc * 64 + ni * 16 + r;
            bv[ni] = *(const bf16x8*)&bc[brow * 32 + ((g ^ ((brow >> 1) & 3)) << 3)];
        }
    }
    __builtin_amdgcn_sched_barrier(0);
    if (t + 1 < nt) {
        const u16* ac = As + ((t + 1) % 3) * 8192;
        #pragma unroll
        for (int mi = 0; mi < 8; mi++) {
            int arow = wr * 128 + mi * 16 + r;
            avW[mi] = *(const bf16x8*)&ac[arow * 32 + ((g ^ ((arow >> 1) & 3)) << 3)];
        }
    }
    if (t + 2 < nt)
        stage256(A, Bt, m0, n0, lda, ldb, (t + 2) << 5,
                 As + ((t + 2) % 3) * 8192, Bs + ((t + 2) % 3) * 8192, tid);
    if (t + 1 < nt) asm volatile("s_waitcnt lgkmcnt(8)" ::: "memory");
    else            asm volatile("s_waitcnt lgkmcnt(0)" ::: "memory");
    __builtin_amdgcn_sched_barrier(0);
    __builtin_amdgcn_s_setprio(1);
    #pragma unroll
    for (int mi = 0; mi < 8; mi++)
        #pragma unroll
        for (int ni = 0; ni < 4; ni++)
            acc[mi][ni] = __builtin_amdgcn_mfma_f32_16x16x32_bf16(avR[mi], bv[ni], acc[mi][ni], 0, 0, 0);
    __builtin_amdgcn_s_setprio(0);
}

// ---------------- 128^2 bf16 MFMA GEMM (pipelined + swizzled) ----------------
// nt = K/32 must be EVEN (holds for all uses: 32/64/8/2).
template<int ACT, bool HAS_BIAS, bool HAS_RES, bool WRITE_BF16, bool WRITE_F32, bool FUSE_FINAL>
__global__ __launch_bounds__(256) void gemm_bf16(
    const u16* __restrict__ A, const u16* __restrict__ Bt,
    float* __restrict__ C, u16* __restrict__ Cbf,
    const float* __restrict__ bias, const float* __restrict__ res,
    const float* __restrict__ xres, const float* __restrict__ rsp,
    int K, int lda, int ldb, int ldc, int Nout, int splitK)
{
    if (splitK) {
        int sp = blockIdx.z;
        A  += (size_t)sp * splitK;
        Bt += (size_t)sp * splitK;
        C  += (size_t)sp * ROWS * ldc;
        K = splitK;
    }
    __shared__ __align__(16) u16 As[3 * 4096];
    __shared__ __align__(16) u16 Bs[3 * 4096];
    const int tid = threadIdx.x;
    const int wv = tid >> 6, ln = tid & 63;
    const int m0 = blockIdx.y * 128, n0 = blockIdx.x * 128;
    const int g = ln >> 4, r = ln & 15;
    const int wr = wv >> 1, wc = wv & 1;

    f32x4 acc[4][4];
    #pragma unroll
    for (int i = 0; i < 4; i++)
        #pragma unroll
        for (int j = 0; j < 4; j++) acc[i][j] = (f32x4)0.f;

    const int nt = K >> 5;
    stage128(A, Bt, m0, n0, lda, ldb, 0,  As,        Bs,        tid);
    stage128(A, Bt, m0, n0, lda, ldb, 32, As + 4096, Bs + 4096, tid);
    asm volatile("s_waitcnt vmcnt(4)" ::: "memory");   // buf0 landed, buf1 in flight
    __builtin_amdgcn_s_barrier();
    __builtin_amdgcn_sched_barrier(0);

    bf16x8 avA[4], avB[4];
    #pragma unroll
    for (int mi = 0; mi < 4; mi++) {
        int arow = wr * 64 + mi * 16 + r;
        avA[mi] = *(const bf16x8*)&As[arow * 32 + ((g ^ ((arow >> 1) & 3)) << 3)];
    }
    for (int tt = 0; tt < nt; tt += 2) {
        ph128(tt,     nt, A, Bt, m0, n0, lda, ldb, tid, wr, wc, g, r, As, Bs, avA, avB, acc);
        ph128(tt + 1, nt, A, Bt, m0, n0, lda, ldb, tid, wr, wc, g, r, As, Bs, avB, avA, acc);
    }

    // C/D layout (verified m89/m91): col = lane&15, row = (lane>>4)*4 + reg
    float rs = FUSE_FINAL ? rsp[0] : 0.f;
    #pragma unroll
    for (int mi = 0; mi < 4; mi++) {
        int row0 = m0 + wr * 64 + mi * 16 + g * 4;
        #pragma unroll
        for (int ni = 0; ni < 4; ni++) {
            int col = n0 + wc * 64 + ni * 16 + r;
            if (col >= Nout) continue;
            float bb = HAS_BIAS ? bias[col] : 0.f;
            #pragma unroll
            for (int j = 0; j < 4; j++) {
                int row = row0 + j;
                float c = acc[mi][ni][j] + bb;
                if (HAS_RES) c += res[(size_t)row * ldc + col];
                if (ACT == 1) c = logf(1.f + __expf(c));       // softplus
                if (FUSE_FINAL) {
                    float yv = res[(size_t)row * ldc + col];   // y2 f32
                    c = xres[(size_t)row * ldc + col] + rs * yv * c;
                }
                if (WRITE_F32 || FUSE_FINAL) C[(size_t)row * ldc + col] = c;
                if (WRITE_BF16) Cbf[(size_t)row * ldc + col] = f2bf(c);
            }
        }
    }
}

// ---------------- 256^2 pipelined bf16 GEMM (in_proj) ----------------
template<bool ZSILU>
__global__ __launch_bounds__(512, 2) void gemm256_bf16(
    const u16* __restrict__ A, const u16* __restrict__ Bt, u16* __restrict__ Cbf,
    int K, int lda, int ldb, int ldc)
{
    __shared__ __align__(16) u16 As[3 * 8192];
    __shared__ __align__(16) u16 Bs[3 * 8192];
    const int tid = threadIdx.x;
    const int wv = tid >> 6, ln = tid & 63;
    const int g = ln >> 4, r = ln & 15;
    const int wr = wv >> 2, wc = wv & 3;
    const int m0 = blockIdx.y * 256, n0 = blockIdx.x * 256;

    f32x4 acc[8][4];
    #pragma unroll
    for (int i = 0; i < 8; i++)
        #pragma unroll
        for (int j = 0; j < 4; j++) acc[i][j] = (f32x4)0.f;

    const int nt = K >> 5;   // even (K=1024 -> 32)
    stage256(A, Bt, m0, n0, lda, ldb, 0,  As,        Bs,        tid);
    stage256(A, Bt, m0, n0, lda, ldb, 32, As + 8192, Bs + 8192, tid);
    asm volatile("s_waitcnt vmcnt(4)" ::: "memory");
    __builtin_amdgcn_s_barrier();
    __builtin_amdgcn_sched_barrier(0);

    bf16x8 avA[8], avB[8];
    #pragma unroll
    for (int mi = 0; mi < 8; mi++) {
        int arow = wr * 128 + mi * 16 + r;
        avA[mi] = *(const bf16x8*)&As[arow * 32 + ((g ^ ((arow >> 1) & 3)) << 3)];
    }
    for (int tt = 0; tt < nt; tt += 2) {
        ph256(tt,     nt, A, Bt, m0, n0, lda, ldb, tid, wr, wc, g, r, As, Bs, avA, avB, acc);
        ph256(tt + 1, nt, A, Bt, m0, n0, lda, ldb, tid, wr, wc, g, r, As, Bs, avB, avA, acc);
    }

    const bool isz = ZSILU && (n0 >= DINNER);
    #pragma unroll
    for (int mi = 0; mi < 8; mi++) {
        int row0 = m0 + wr * 128 + mi * 16 + g * 4;
        #pragma unroll
        for (int ni = 0; ni < 4; ni++) {
            int col = n0 + wc * 64 + ni * 16 + r;
            #pragma unroll
            for (int j = 0; j < 4; j++) {
                float c = acc[mi][ni][j];
                if (isz) c = silu_f(c);
                Cbf[(size_t)(row0 + j) * ldc + col] = f2bf(c);
            }
        }
    }
}

// ---------------- Reduce split-K partials for x_proj (8 slabs) ----------------
__global__ __launch_bounds__(256) void reduce_xproj(const float* __restrict__ part,
                                                    float* __restrict__ xdbl,
                                                    u16* __restrict__ xdbl_bf)
{
    int i = blockIdx.x * 256 + threadIdx.x;  // ROWS*96
    const int SL = ROWS * 96;
    float s = 0.f;
    #pragma unroll
    for (int k = 0; k < 8; k++) s += part[i + k * SL];
    xdbl[i] = s;
    xdbl_bf[i] = f2bf(s);
}

// ---------------- Causal depthwise conv (d_conv=4) + SiLU -> bf16 u ----------------
__global__ __launch_bounds__(256) void conv_silu_kernel(
    const u16* __restrict__ xzbf, const float* __restrict__ w,
    const float* __restrict__ b, u16* __restrict__ u)
{
    size_t idx = (size_t)blockIdx.x * 256 + threadIdx.x;  // ROWS*DINNER
    int d = (int)(idx & (DINNER - 1));
    int r = (int)(idx >> 11);
    int t = r & (SEQ - 1);
    float4 wv = *(const float4*)(w + (size_t)d * 4);
    float acc = b[d];
    const float* wf = (const float*)&wv;
    #pragma unroll
    for (int j = 0; j < 4; j++) {
        int tt = t - 3 + j;
        if (tt >= 0)
            acc = fmaf(bf2f(xzbf[(size_t)(r - 3 + j) * 4096 + d]), wf[j], acc);
    }
    u[idx] = f2bf(silu_f(acc));
}

// ---------------- Chunked selective scan (fp32 state; bf16 delta/u/z) ----------------
__global__ __launch_bounds__(256) void scan_phaseA(
    const u16* __restrict__ delta,
    const u16* __restrict__ u,
    const float* __restrict__ xdbl,   // [ROWS,96]; B at +64
    const float* __restrict__ A_log,
    float* __restrict__ S, float* __restrict__ sumdlt)
{
    int d = blockIdx.x * 256 + threadIdx.x;
    int c = blockIdx.y, b = blockIdx.z;
    float Ad[NSTATE];
    #pragma unroll
    for (int n = 0; n < NSTATE; n++) Ad[n] = -__expf(A_log[(size_t)d * NSTATE + n]);
    float hs[NSTATE];
    #pragma unroll
    for (int n = 0; n < NSTATE; n++) hs[n] = 0.f;
    float sd = 0.f;
    int r0 = b * SEQ + c * TS;
    for (int t = 0; t < TS; t++) {
        int r = r0 + t;
        float dlt = bf2f(delta[(size_t)r * DINNER + d]);
        float uu  = bf2f(u[(size_t)r * DINNER + d]);
        const float* bm = xdbl + (size_t)r * 96 + DTRANK;
        float du = dlt * uu;
        sd += dlt;
        #pragma unroll
        for (int n = 0; n < NSTATE; n++) {
            float dA = __expf(dlt * Ad[n]);
            hs[n] = fmaf(dA, hs[n], du * bm[n]);
        }
    }
    size_t base = ((size_t)(b * NC + c) * DINNER + d) * NSTATE;
    #pragma unroll
    for (int n = 0; n < NSTATE; n += 4)
        *(float4*)(S + base + n) = make_float4(hs[n], hs[n+1], hs[n+2], hs[n+3]);
    sumdlt[(size_t)(b * NC + c) * DINNER + d] = sd;
}

__global__ __launch_bounds__(256) void scan_phaseB(
    const float* __restrict__ S, const float* __restrict__ sumdlt,
    const float* __restrict__ A_log, float* __restrict__ Hin)
{
    int idx = blockIdx.x * 256 + threadIdx.x;   // BATCH*DINNER*NSTATE
    int b  = idx >> 15;
    int dn = idx & (DINNER * NSTATE - 1);
    float Ad = -__expf(A_log[dn]);
    int d = dn >> 4;
    const size_t stride = (size_t)DINNER * NSTATE;
    size_t base  = (size_t)b * NC * stride + dn;
    size_t sbase = (size_t)b * NC * DINNER + d;
    float h = 0.f;
    for (int c = 0; c < NC; c++) {
        size_t off = base + (size_t)c * stride;
        float p = __expf(Ad * sumdlt[sbase + (size_t)c * DINNER]);
        float s = S[off];
        Hin[off] = h;
        h = fmaf(p, h, s);
    }
}

__global__ __launch_bounds__(256) void scan_phaseC(
    const u16* __restrict__ delta,
    u16* __restrict__ u,              // in: u (bf16); out: yz (bf16, in-place)
    const float* __restrict__ xdbl,   // B at +64, C at +80
    const float* __restrict__ A_log,
    const float* __restrict__ Hin,
    const float* __restrict__ Dp,
    const u16* __restrict__ xzbf)     // silu(z) at col 2048+d, ld 4096 (pre-gated)
{
    int d = blockIdx.x * 256 + threadIdx.x;
    int c = blockIdx.y, b = blockIdx.z;
    float Ad[NSTATE];
    #pragma unroll
    for (int n = 0; n < NSTATE; n++) Ad[n] = -__expf(A_log[(size_t)d * NSTATE + n]);
    float hs[NSTATE];
    size_t hbase = ((size_t)(b * NC + c) * DINNER + d) * NSTATE;
    #pragma unroll
    for (int n = 0; n < NSTATE; n++) hs[n] = Hin[hbase + n];
    float Dd = Dp[d];
    int r0 = b * SEQ + c * TS;
    for (int t = 0; t < TS; t++) {
        int r = r0 + t;
        float dlt = bf2f(delta[(size_t)r * DINNER + d]);
        float uu  = bf2f(u[(size_t)r * DINNER + d]);
        const float* bm = xdbl + (size_t)r * 96 + DTRANK;
        const float* cm = bm + NSTATE;
        float du = dlt * uu;
        float y = 0.f;
        #pragma unroll
        for (int n = 0; n < NSTATE; n++) {
            float dA = __expf(dlt * Ad[n]);
            hs[n] = fmaf(dA, hs[n], du * bm[n]);
            y = fmaf(hs[n], cm[n], y);
        }
        float sz = bf2f(xzbf[(size_t)r * 4096 + DINNER + d]);
        u[(size_t)r * DINNER + d] = f2bf((y + uu * Dd) * sz);
    }
}

extern "C" void kernel_launch(void* const* d_in, const int* in_sizes, int n_in,
                              void* d_out, int out_size, void* d_ws, size_t ws_size,
                              hipStream_t stream)
{
    const float* x         = (const float*)d_in[0];
    const float* ln_g      = (const float*)d_in[1];
    const float* ln_b      = (const float*)d_in[2];
    const float* sq_w      = (const float*)d_in[3];
    const float* sq_b      = (const float*)d_in[4];
    const float* srw_w     = (const float*)d_in[5];
    const float* srw_b     = (const float*)d_in[6];
    const float* res_scale = (const float*)d_in[7];
    const float* in_proj_w = (const float*)d_in[8];
    const float* conv_w    = (const float*)d_in[9];
    const float* conv_b    = (const float*)d_in[10];
    const float* x_proj_w  = (const float*)d_in[11];
    const float* dt_w      = (const float*)d_in[12];
    const float* dt_b      = (const float*)d_in[13];
    const float* A_log     = (const float*)d_in[14];
    const float* Dp        = (const float*)d_in[15];
    const float* out_proj_w= (const float*)d_in[16];
    float* out = (float*)d_out;

    char* ws = (char*)d_ws;
    float* h0      = (float*)(ws + 0);
    u16*   delta_bf= (u16*)  (ws + 0);
    float* y2      = (float*)(ws + 0);
    float* xpart   = (float*)(ws + ((size_t)16 << 20));
    u16*   xz_bf   = (u16*)  (ws + ((size_t)32 << 20));
    u16*   u_bf    = (u16*)  (ws + ((size_t)64 << 20));
    float* xdbl    = (float*)(ws + ((size_t)80 << 20));
    u16*   xprojT  = (u16*)  (ws + ((size_t)82 << 20));
    u16*   h0_bf   = (u16*)  (ws + ((size_t)83 << 20));
    u16*   xdbl_bf = (u16*)  (ws + ((size_t)83 << 20));
    u16*   h_bf    = (u16*)  (ws + ((size_t)91 << 20));
    float* sumdlt  = (float*)(ws + ((size_t)91 << 20));
    float* S       = (float*)(ws + ((size_t)99 << 20));
    u16*   y2_bf   = (u16*)  (ws + ((size_t)99 << 20));
    float* Hin     = (float*)(ws + ((size_t)115 << 20));
    u16*   sqT     = (u16*)  (ws + ((size_t)131 << 20));
    u16*   srwT    = (u16*)  (ws + ((size_t)133 << 20));
    u16*   inprojT = (u16*)  (ws + ((size_t)135 << 20));
    u16*   outprojT= (u16*)  (ws + ((size_t)143 << 20));
    u16*   dtT     = (u16*)  (ws + ((size_t)147 << 20));

    dim3 blk(256);

    // 0+1) weight transposes + LayerNorm, one dispatch
    prologue_kernel<<<8576 + ROWS, blk, 0, stream>>>(
        sq_w, sqT, srw_w, srwT, in_proj_w, inprojT, out_proj_w, outprojT,
        x_proj_w, xprojT, dt_w, dtT, x, ln_g, ln_b, h0, h0_bf);
    // 2) h_bf = bf16(h0 + h0@sq_w + sq_b)
    gemm_bf16<0, true, true, true, false, false><<<dim3(8, 32), blk, 0, stream>>>(
        h0_bf, sqT, nullptr, h_bf, sq_b, h0, nullptr, nullptr, DMODEL, DMODEL, DMODEL, DMODEL, DMODEL, 0);
    // 3) xz_bf = bf16(h @ in_proj_w), silu fused onto z-half — pipelined 256^2 kernel
    gemm256_bf16<true><<<dim3(16, 16), dim3(512), 0, stream>>>(
        h_bf, inprojT, xz_bf, DMODEL, DMODEL, DMODEL, 2 * DINNER);
    // 4) u_bf = bf16(silu(causal_dwconv(xz_bf[:, :2048])))
    conv_silu_kernel<<<(ROWS * DINNER) / 256, blk, 0, stream>>>(xz_bf, conv_w, conv_b, u_bf);
    // 5) x_proj split-K=8: partials -> xpart, then reduce
    gemm_bf16<0, false, false, false, true, false><<<dim3(1, 32, 8), blk, 0, stream>>>(
        u_bf, xprojT, xpart, nullptr, nullptr, nullptr, nullptr, nullptr,
        DINNER, DINNER, DINNER, 96, 96, DINNER / 8);
    reduce_xproj<<<(ROWS * 96) / 256, blk, 0, stream>>>(xpart, xdbl, xdbl_bf);
    // 6) delta_bf = bf16(softplus(xdbl[:, :64] @ dt_w + dt_b))
    gemm_bf16<1, true, false, true, false, false><<<dim3(16, 32), blk, 0, stream>>>(
        xdbl_bf, dtT, nullptr, delta_bf, dt_b, nullptr, nullptr, nullptr,
        DTRANK, 96, DTRANK, DINNER, DINNER, 0);
    // 7-9) chunked scan (fp32 state)
    scan_phaseA<<<dim3(DINNER / 256, NC, BATCH), blk, 0, stream>>>(delta_bf, u_bf, xdbl, A_log, S, sumdlt);
    scan_phaseB<<<dim3((BATCH * DINNER * NSTATE) / 256), blk, 0, stream>>>(S, sumdlt, A_log, Hin);
    scan_phaseC<<<dim3(DINNER / 256, NC, BATCH), blk, 0, stream>>>(delta_bf, u_bf, xdbl, A_log, Hin, Dp, xz_bf);
    // 10) y2 = yz @ out_proj_w  (f32 + bf16)
    gemm_bf16<0, false, false, true, true, false><<<dim3(8, 32), blk, 0, stream>>>(
        u_bf, outprojT, y2, y2_bf, nullptr, nullptr, nullptr, nullptr,
        DINNER, DINNER, DINNER, DMODEL, DMODEL, 0);
    // 11+12) out = x + rs * (y2 * (y2@srw_w + srw_b))  — fused epilogue
    gemm_bf16<0, true, false, false, false, true><<<dim3(8, 32), blk, 0, stream>>>(
        y2_bf, srwT, out, nullptr, srw_b, y2, x, res_scale,
        DMODEL, DMODEL, DMODEL, DMODEL, DMODEL, 0);
}